// Round 1
// baseline (382.275 us; speedup 1.0000x reference)
//
#include <hip/hip_runtime.h>

#define NB 4
#define SS 2048
#define DM 512
#define DD 64
#define QB 16
#define KBL 64

// ---------------- mask dtype detection ----------------
__global__ __launch_bounds__(64) void init_flags(int* viol) {
  if (threadIdx.x < 3) viol[threadIdx.x] = 0;
}

__global__ __launch_bounds__(256) void detect_mask(const unsigned* __restrict__ mw,
                                                   int nwords, int* __restrict__ viol) {
  int stride = gridDim.x * blockDim.x;
  int vi = 0, vf = 0, vu = 0;
  for (int i = blockIdx.x * blockDim.x + threadIdx.x; i < nwords; i += stride) {
    unsigned w = mw[i];
    vi |= (w > 1u);
    vf |= ((w != 0u) & (w != 0x3F800000u));
    vu |= ((w & 0xFEFEFEFEu) != 0u);   // any byte outside {0,1}
  }
  int lane = threadIdx.x & 63;
  unsigned long long b;
  b = __ballot(vi); if (lane == 0 && b) atomicOr(&viol[0], 1);
  b = __ballot(vf); if (lane == 0 && b) atomicOr(&viol[1], 1);
  b = __ballot(vu); if (lane == 0 && b) atomicOr(&viol[2], 1);
}

// ---------------- input projections: [8192,512] @ [512,64] ----------------
__global__ __launch_bounds__(256) void proj_kernel(
    const float* __restrict__ q, const float* __restrict__ k, const float* __restrict__ v,
    const float* __restrict__ Wq, const float* __restrict__ bq,
    const float* __restrict__ Wk, const float* __restrict__ bk,
    const float* __restrict__ Wv, const float* __restrict__ bv,
    float* __restrict__ qp, float* __restrict__ kp, float* __restrict__ vp) {
  const int which = blockIdx.y;
  const float* X; const float* W; const float* bias; float* out;
  if (which == 0)      { X = q; W = Wq; bias = bq; out = qp; }
  else if (which == 1) { X = k; W = Wk; bias = bk; out = kp; }
  else                 { X = v; W = Wv; bias = bv; out = vp; }
  const int row0 = blockIdx.x * 16;
  const int tid = threadIdx.x;
  __shared__ float xs[16][516];                 // stride 516: (4r+i)%32 banks, f4-aligned
  #pragma unroll
  for (int p = 0; p < 8; ++p) {
    int f = tid + 256 * p;                      // float4 id 0..2047
    int r = f >> 7;
    int i = (f & 127) << 2;
    float4 val = *(const float4*)(X + (size_t)(row0 + r) * DM + i);
    *(float4*)&xs[r][i] = val;
  }
  __syncthreads();
  const int r = tid >> 4, cq = tid & 15, c0 = cq << 2;
  float4 acc = *(const float4*)(bias + c0);
  #pragma unroll 4
  for (int i = 0; i < DM; i += 4) {
    float4 xv = *(float4*)&xs[r][i];
    float4 w0 = *(const float4*)(W + (size_t)(i    ) * DD + c0);
    float4 w1 = *(const float4*)(W + (size_t)(i + 1) * DD + c0);
    float4 w2 = *(const float4*)(W + (size_t)(i + 2) * DD + c0);
    float4 w3 = *(const float4*)(W + (size_t)(i + 3) * DD + c0);
    acc.x += xv.x * w0.x + xv.y * w1.x + xv.z * w2.x + xv.w * w3.x;
    acc.y += xv.x * w0.y + xv.y * w1.y + xv.z * w2.y + xv.w * w3.y;
    acc.z += xv.x * w0.z + xv.y * w1.z + xv.z * w2.z + xv.w * w3.z;
    acc.w += xv.x * w0.w + xv.y * w1.w + xv.z * w2.w + xv.w * w3.w;
  }
  *(float4*)(out + (size_t)(row0 + r) * DD + c0) = acc;
}

// ---------------- fused flash attention (fp32) ----------------
__global__ __launch_bounds__(256) void attn_kernel(
    const float* __restrict__ qp, const float* __restrict__ kp, const float* __restrict__ vp,
    const float* __restrict__ g_bias, const void* __restrict__ mask,
    const int* __restrict__ viol, const float* __restrict__ tau,
    float* __restrict__ aout) {
  const int b = blockIdx.y;
  const int q0 = blockIdx.x * QB;
  const int tid = threadIdx.x;
  const int rp = tid >> 4;                       // q-row within tile (0..15)
  const int c0 = (tid & 15) << 2;                // col quad (0..60)
  const int mode = (viol[0] == 0) ? 0 : ((viol[1] == 0) ? 1 : 2);
  const float tv = tau[0];
  const float bscale = 1.0f / (2.0f * tv * tv);

  __shared__ float q_s[QB][68];                  // [row][dim], stride 68
  __shared__ float k_t[DD][68];                  // TRANSPOSED [dim][key], stride 68
  __shared__ float v_s[KBL][DD];                 // [key][dim]
  __shared__ float p_s[QB][68];

  { // stage q tile: 256 float4s, one per thread
    int r = tid >> 4, i = (tid & 15) << 2;
    float4 val = *(const float4*)(qp + (size_t)(b * SS + q0 + r) * DD + i);
    *(float4*)&q_s[r][i] = val;
  }

  const size_t rowoff = (size_t)(b * SS + q0 + rp) * SS;  // g_bias/mask row for my q-row
  const float* gbrow = g_bias + rowoff;
  const float* kpb = kp + (size_t)b * SS * DD;
  const float* vpb = vp + (size_t)b * SS * DD;

  float m_r = -1e30f, l_r = 0.0f;
  float4 acc_o = {0.f, 0.f, 0.f, 0.f};

  for (int k0 = 0; k0 < SS; k0 += KBL) {
    __syncthreads();                             // prev PV done before overwrite
    #pragma unroll
    for (int p = 0; p < 4; ++p) {                // stage kT (transposed) + v
      int f = tid + 256 * p;                     // 0..1023
      int c = f >> 4, i0 = (f & 15) << 2;
      float4 val = *(const float4*)(kpb + (size_t)(k0 + c) * DD + i0);
      k_t[i0    ][c] = val.x;
      k_t[i0 + 1][c] = val.y;
      k_t[i0 + 2][c] = val.z;
      k_t[i0 + 3][c] = val.w;
      float4 vv = *(const float4*)(vpb + (size_t)(k0 + c) * DD + i0);
      *(float4*)&v_s[c][i0] = vv;
    }
    // prefetch bias + mask for my 4 logits (issued before the dot loop)
    float4 gb = *(const float4*)(gbrow + k0 + c0);
    int m0, m1, m2, m3;
    if (mode == 0) {
      int4 mi = *(const int4*)((const int*)mask + rowoff + k0 + c0);
      m0 = (mi.x != 0); m1 = (mi.y != 0); m2 = (mi.z != 0); m3 = (mi.w != 0);
    } else if (mode == 1) {
      float4 mf = *(const float4*)((const float*)mask + rowoff + k0 + c0);
      m0 = (mf.x != 0.f); m1 = (mf.y != 0.f); m2 = (mf.z != 0.f); m3 = (mf.w != 0.f);
    } else {
      unsigned mu = *(const unsigned*)((const unsigned char*)mask + rowoff + k0 + c0);
      m0 = (mu & 0xFFu) != 0; m1 = (mu & 0xFF00u) != 0;
      m2 = (mu & 0xFF0000u) != 0; m3 = (mu & 0xFF000000u) != 0;
    }
    __syncthreads();

    // ---- QK^T: acc[c'] = sum_i q_s[rp][i] * k_t[i][c0+c']
    float4 acc = {0.f, 0.f, 0.f, 0.f};
    #pragma unroll 4
    for (int i = 0; i < DD; i += 4) {
      float4 qv = *(float4*)&q_s[rp][i];
      float4 ka = *(float4*)&k_t[i    ][c0];
      float4 kb = *(float4*)&k_t[i + 1][c0];
      float4 kc = *(float4*)&k_t[i + 2][c0];
      float4 kd = *(float4*)&k_t[i + 3][c0];
      acc.x += qv.x * ka.x + qv.y * kb.x + qv.z * kc.x + qv.w * kd.x;
      acc.y += qv.x * ka.y + qv.y * kb.y + qv.z * kc.y + qv.w * kd.y;
      acc.z += qv.x * ka.z + qv.y * kb.z + qv.z * kc.z + qv.w * kd.z;
      acc.w += qv.x * ka.w + qv.y * kb.w + qv.z * kc.w + qv.w * kd.w;
    }
    float s0 = m0 ? -1e30f : (acc.x * 0.125f + gb.x * bscale);
    float s1 = m1 ? -1e30f : (acc.y * 0.125f + gb.y * bscale);
    float s2 = m2 ? -1e30f : (acc.z * 0.125f + gb.z * bscale);
    float s3 = m3 ? -1e30f : (acc.w * 0.125f + gb.w * bscale);

    // ---- online softmax over the 16 lanes owning this row
    float mx = fmaxf(fmaxf(s0, s1), fmaxf(s2, s3));
    #pragma unroll
    for (int off = 1; off < 16; off <<= 1) mx = fmaxf(mx, __shfl_xor(mx, off));
    float m_new = fmaxf(m_r, mx);
    float p0 = (s0 < -1e29f) ? 0.f : __expf(s0 - m_new);
    float p1 = (s1 < -1e29f) ? 0.f : __expf(s1 - m_new);
    float p2 = (s2 < -1e29f) ? 0.f : __expf(s2 - m_new);
    float p3 = (s3 < -1e29f) ? 0.f : __expf(s3 - m_new);
    float sum = p0 + p1 + p2 + p3;
    #pragma unroll
    for (int off = 1; off < 16; off <<= 1) sum += __shfl_xor(sum, off);
    float scale = __expf(m_r - m_new);
    l_r = l_r * scale + sum;
    m_r = m_new;
    acc_o.x *= scale; acc_o.y *= scale; acc_o.z *= scale; acc_o.w *= scale;
    float4 pw = {p0, p1, p2, p3};
    *(float4*)&p_s[rp][c0] = pw;
    __syncthreads();

    // ---- PV: acc_o[d'] += sum_k p_s[rp][k] * v_s[k][c0+d']
    #pragma unroll 4
    for (int kk = 0; kk < KBL; kk += 4) {
      float4 pv = *(float4*)&p_s[rp][kk];
      float4 v0 = *(float4*)&v_s[kk    ][c0];
      float4 v1 = *(float4*)&v_s[kk + 1][c0];
      float4 v2 = *(float4*)&v_s[kk + 2][c0];
      float4 v3 = *(float4*)&v_s[kk + 3][c0];
      acc_o.x += pv.x * v0.x + pv.y * v1.x + pv.z * v2.x + pv.w * v3.x;
      acc_o.y += pv.x * v0.y + pv.y * v1.y + pv.z * v2.y + pv.w * v3.y;
      acc_o.z += pv.x * v0.z + pv.y * v1.z + pv.z * v2.z + pv.w * v3.z;
      acc_o.w += pv.x * v0.w + pv.y * v1.w + pv.z * v2.w + pv.w * v3.w;
    }
  }
  float inv_l = (l_r > 0.f) ? (1.0f / l_r) : 0.f;
  float4 o = {acc_o.x * inv_l, acc_o.y * inv_l, acc_o.z * inv_l, acc_o.w * inv_l};
  *(float4*)(aout + (size_t)(b * SS + q0 + rp) * DD + c0) = o;
}

// ---------------- output projection: [8192,64] @ [64,512] ----------------
__global__ __launch_bounds__(256) void fc_kernel(
    const float* __restrict__ aout, const float* __restrict__ Wfc,
    const float* __restrict__ bfc, float* __restrict__ out) {
  const int tid = threadIdx.x;
  __shared__ float a_s[2][DD];
  if (tid < 128) {
    a_s[tid >> 6][tid & 63] =
        aout[(size_t)(blockIdx.x * 2 + (tid >> 6)) * DD + (tid & 63)];
  }
  __syncthreads();
  const int half = tid >> 7;
  const int row = blockIdx.x * 2 + half;
  const int c0 = (tid & 127) << 2;
  float4 acc = *(const float4*)(bfc + c0);
  #pragma unroll 4
  for (int i = 0; i < DD; ++i) {
    float av = a_s[half][i];
    float4 wv = *(const float4*)(Wfc + (size_t)i * DM + c0);
    acc.x += av * wv.x; acc.y += av * wv.y; acc.z += av * wv.z; acc.w += av * wv.w;
  }
  *(float4*)(out + (size_t)row * DM + c0) = acc;
}

extern "C" void kernel_launch(void* const* d_in, const int* in_sizes, int n_in,
                              void* d_out, int out_size, void* d_ws, size_t ws_size,
                              hipStream_t stream) {
  const float* q    = (const float*)d_in[0];
  const float* k    = (const float*)d_in[1];
  const float* v    = (const float*)d_in[2];
  const float* gb   = (const float*)d_in[3];
  const void*  mask = d_in[4];
  const float* Wq   = (const float*)d_in[5];
  const float* bq   = (const float*)d_in[6];
  const float* Wk   = (const float*)d_in[7];
  const float* bk   = (const float*)d_in[8];
  const float* Wv   = (const float*)d_in[9];
  const float* bv   = (const float*)d_in[10];
  const float* Wfc  = (const float*)d_in[11];
  const float* bfc  = (const float*)d_in[12];
  const float* tau  = (const float*)d_in[13];
  float* out = (float*)d_out;

  int* viol = (int*)d_ws;
  float* qp   = (float*)((char*)d_ws + 256);
  float* kp   = qp + (size_t)NB * SS * DD;
  float* vp   = kp + (size_t)NB * SS * DD;
  float* aout = vp + (size_t)NB * SS * DD;

  const int nwords = in_sizes[4] / 4;   // safe to read in all candidate dtypes

  init_flags<<<1, 64, 0, stream>>>(viol);
  detect_mask<<<2048, 256, 0, stream>>>((const unsigned*)mask, nwords, viol);
  proj_kernel<<<dim3((NB * SS) / 16, 3), 256, 0, stream>>>(
      q, k, v, Wq, bq, Wk, bk, Wv, bv, qp, kp, vp);
  attn_kernel<<<dim3(SS / QB, NB), 256, 0, stream>>>(
      qp, kp, vp, gb, mask, viol, tau, aout);
  fc_kernel<<<(NB * SS) / 2, 256, 0, stream>>>(aout, Wfc, bfc, out);
}

// Round 3
// 132.132 us; speedup vs baseline: 2.8931x; 2.8931x over previous
//
#include <hip/hip_runtime.h>

#define NB 4
#define SS 2048
#define DM 512
#define DD 64
#define NR (NB*SS)

typedef __attribute__((ext_vector_type(8))) short bf16x8;
typedef __attribute__((ext_vector_type(4))) float f32x4;

static __device__ __forceinline__ unsigned short f2b(float f) {
  union { float f; unsigned u; } x; x.f = f;
  unsigned r = x.u + 0x7FFFu + ((x.u >> 16) & 1u);
  return (unsigned short)(r >> 16);
}
static __device__ __forceinline__ bf16x8 ld8(const unsigned short* p) {
  union { uint4 u; bf16x8 v; } x; x.u = *(const uint4*)p; return x.v;
}

// ---------------- mask dtype detection ----------------
__global__ __launch_bounds__(64) void init_flags(int* viol) {
  if (threadIdx.x < 3) viol[threadIdx.x] = 0;
}

__global__ __launch_bounds__(256) void detect_mask(const unsigned* __restrict__ mw,
                                                   int nwords, int* __restrict__ viol) {
  int stride = gridDim.x * blockDim.x;
  int vi = 0, vf = 0, vu = 0;
  for (int i = blockIdx.x * blockDim.x + threadIdx.x; i < nwords; i += stride) {
    unsigned w = mw[i];
    vi |= (w > 1u);
    vf |= ((w != 0u) & (w != 0x3F800000u));
    vu |= ((w & 0xFEFEFEFEu) != 0u);
  }
  int lane = threadIdx.x & 63;
  unsigned long long b;
  b = __ballot(vi); if (lane == 0 && b) atomicOr(&viol[0], 1);
  b = __ballot(vf); if (lane == 0 && b) atomicOr(&viol[1], 1);
  b = __ballot(vu); if (lane == 0 && b) atomicOr(&viol[2], 1);
}

// ---------------- W transpose: Wt[p][n=64][k=512] bf16 <- W[k][n] fp32 ----------------
__global__ __launch_bounds__(256) void transpose_w(
    const float* __restrict__ Wq, const float* __restrict__ Wk, const float* __restrict__ Wv,
    unsigned short* __restrict__ Wt) {
  const int p = blockIdx.y;
  const float* W = (p == 0) ? Wq : ((p == 1) ? Wk : Wv);
  const int k0 = blockIdx.x * 64;
  const int t = threadIdx.x;
  const int n0 = (t & 15) * 4;
  #pragma unroll
  for (int p2 = 0; p2 < 4; ++p2) {
    int k = k0 + (t >> 4) + 16 * p2;
    float4 w = *(const float4*)(W + (size_t)k * DD + n0);
    Wt[(size_t)(p * DD + n0 + 0) * DM + k] = f2b(w.x);
    Wt[(size_t)(p * DD + n0 + 1) * DM + k] = f2b(w.y);
    Wt[(size_t)(p * DD + n0 + 2) * DM + k] = f2b(w.z);
    Wt[(size_t)(p * DD + n0 + 3) * DM + k] = f2b(w.w);
  }
}

// ---------------- projections via MFMA: [8192,512]@[512,64] -> bf16 ----------------
__global__ __launch_bounds__(256, 4) void proj_mfma(
    const float* __restrict__ q, const float* __restrict__ k, const float* __restrict__ v,
    const unsigned short* __restrict__ Wt,
    const float* __restrict__ bq, const float* __restrict__ bk, const float* __restrict__ bv,
    unsigned short* __restrict__ qp, unsigned short* __restrict__ kp,
    unsigned short* __restrict__ vp) {
  const int p = blockIdx.y;
  const float* X = (p == 0) ? q : ((p == 1) ? k : v);
  const float* bias = (p == 0) ? bq : ((p == 1) ? bk : bv);
  unsigned short* out = (p == 0) ? qp : ((p == 1) ? kp : vp);
  const int row0 = blockIdx.x * 64;
  const int tid = threadIdx.x;
  const int wq = tid >> 6, lane = tid & 63, g = lane >> 4, c = lane & 15;
  __shared__ unsigned short x_s[64][72];
  f32x4 acc[4];
  #pragma unroll
  for (int s = 0; s < 4; ++s) acc[s] = (f32x4){0.f, 0.f, 0.f, 0.f};
  const unsigned short* wbase = Wt + (size_t)p * DD * DM;

  for (int k0 = 0; k0 < DM; k0 += 64) {
    __syncthreads();
    #pragma unroll
    for (int pp = 0; pp < 4; ++pp) {
      int f = tid + 256 * pp;
      int r = f >> 4, c4 = (f & 15) * 4;
      float4 xv = *(const float4*)(X + (size_t)(row0 + r) * DM + k0 + c4);
      uint2 u;
      u.x = (unsigned)f2b(xv.x) | ((unsigned)f2b(xv.y) << 16);
      u.y = (unsigned)f2b(xv.z) | ((unsigned)f2b(xv.w) << 16);
      *(uint2*)&x_s[r][c4] = u;
    }
    __syncthreads();
    const unsigned short* xrow = &x_s[wq * 16 + c][0];
    bf16x8 a0 = ld8(xrow + 8 * g);
    bf16x8 a1 = ld8(xrow + 32 + 8 * g);
    #pragma unroll
    for (int s = 0; s < 4; ++s) {
      const unsigned short* wrow = wbase + (size_t)(16 * s + c) * DM + k0;
      bf16x8 b0 = ld8(wrow + 8 * g);
      bf16x8 b1 = ld8(wrow + 32 + 8 * g);
      acc[s] = __builtin_amdgcn_mfma_f32_16x16x32_bf16(a0, b0, acc[s], 0, 0, 0);
      acc[s] = __builtin_amdgcn_mfma_f32_16x16x32_bf16(a1, b1, acc[s], 0, 0, 0);
    }
  }
  #pragma unroll
  for (int s = 0; s < 4; ++s) {
    float bs = bias[16 * s + c];
    #pragma unroll
    for (int r = 0; r < 4; ++r) {
      int row = row0 + wq * 16 + 4 * g + r;
      out[(size_t)row * DD + 16 * s + c] = f2b(acc[s][r] + bs);
    }
  }
}

// ---------------- flash attention via MFMA, k-split partials ----------------
__global__ __launch_bounds__(256, 4) void attn_mfma(
    const unsigned short* __restrict__ qp, const unsigned short* __restrict__ kp,
    const unsigned short* __restrict__ vp, const float* __restrict__ g_bias,
    const void* __restrict__ mask, const int* __restrict__ viol,
    const float* __restrict__ tau, float* __restrict__ part_o,
    float* __restrict__ part_ml, int nks) {
  const int b = blockIdx.y;
  const int qb = blockIdx.x / nks;
  const int ks = blockIdx.x - qb * nks;
  const int tid = threadIdx.x;
  const int wq = tid >> 6, lane = tid & 63, g = lane >> 4, c = lane & 15;
  const int qw = qb * 64 + wq * 16;
  const int klen = SS / nks, kbeg = ks * klen;
  const int mode = (viol[0] == 0) ? 0 : ((viol[1] == 0) ? 1 : 2);
  const float tv = tau[0];
  const float bscale = 1.0f / (2.0f * tv * tv);

  __shared__ unsigned short k_s[64][72];
  __shared__ unsigned short v_t[64][72];
  __shared__ unsigned short p_s[4][16][72];

  const unsigned short* qrow = qp + (size_t)(b * SS + qw + c) * DD;
  bf16x8 qf0 = ld8(qrow + 8 * g);
  bf16x8 qf1 = ld8(qrow + 32 + 8 * g);

  size_t rb[4];
  #pragma unroll
  for (int r = 0; r < 4; ++r) rb[r] = (size_t)(b * SS + qw + 4 * g + r) * SS;

  float m_r[4] = {-1e30f, -1e30f, -1e30f, -1e30f};
  float l_r[4] = {0.f, 0.f, 0.f, 0.f};
  f32x4 o[4];
  #pragma unroll
  for (int s = 0; s < 4; ++s) o[s] = (f32x4){0.f, 0.f, 0.f, 0.f};

  for (int kt = 0; kt < klen; kt += 64) {
    const int k0 = kbeg + kt;
    __syncthreads();
    {  // stage K tile [key][dk] (full 64x64!) and V tile transposed [dv][key]
      int row = tid >> 2, ch = tid & 3;
      const unsigned short* ksrc = kp + (size_t)(b * SS + k0 + row) * DD + 8 * ch;
      *(uint4*)&k_s[row][8 * ch] = *(const uint4*)ksrc;
      *(uint4*)&k_s[row][32 + 8 * ch] = *(const uint4*)(ksrc + 32);
      int kk = (tid & 31) * 2, dv0 = (tid >> 5) * 8;
      const unsigned short* va = vp + (size_t)(b * SS + k0 + kk) * DD + dv0;
      uint4 aa = *(const uint4*)va;
      uint4 bb = *(const uint4*)(va + DD);
      unsigned au[4] = {aa.x, aa.y, aa.z, aa.w};
      unsigned bu[4] = {bb.x, bb.y, bb.z, bb.w};
      #pragma unroll
      for (int i = 0; i < 4; ++i) {
        *(unsigned*)&v_t[dv0 + 2 * i][kk] = (au[i] & 0xFFFFu) | (bu[i] << 16);
        *(unsigned*)&v_t[dv0 + 2 * i + 1][kk] = (au[i] >> 16) | (bu[i] & 0xFFFF0000u);
      }
    }
    // bias + mask loads for my 16 logits (issued early, consumed post-MFMA)
    float bv[16];
    unsigned mb = 0;
    if (mode == 0) {
      const int* mp = (const int*)mask;
      #pragma unroll
      for (int i = 0; i < 16; ++i) {
        size_t idx = rb[i & 3] + k0 + 16 * (i >> 2) + c;
        bv[i] = g_bias[idx];
        mb |= (mp[idx] != 0) ? (1u << i) : 0u;
      }
    } else if (mode == 1) {
      const float* mp = (const float*)mask;
      #pragma unroll
      for (int i = 0; i < 16; ++i) {
        size_t idx = rb[i & 3] + k0 + 16 * (i >> 2) + c;
        bv[i] = g_bias[idx];
        mb |= (mp[idx] != 0.f) ? (1u << i) : 0u;
      }
    } else {
      const unsigned char* mp = (const unsigned char*)mask;
      #pragma unroll
      for (int i = 0; i < 16; ++i) {
        size_t idx = rb[i & 3] + k0 + 16 * (i >> 2) + c;
        bv[i] = g_bias[idx];
        mb |= (mp[idx] != 0) ? (1u << i) : 0u;
      }
    }
    __syncthreads();

    // ---- QK^T: S[q=4g+r][key=16s+c]
    f32x4 sa[4];
    #pragma unroll
    for (int s = 0; s < 4; ++s) sa[s] = (f32x4){0.f, 0.f, 0.f, 0.f};
    #pragma unroll
    for (int s = 0; s < 4; ++s) {
      const unsigned short* krow = &k_s[16 * s + c][0];
      bf16x8 b0 = ld8(krow + 8 * g);
      bf16x8 b1 = ld8(krow + 32 + 8 * g);
      sa[s] = __builtin_amdgcn_mfma_f32_16x16x32_bf16(qf0, b0, sa[s], 0, 0, 0);
      sa[s] = __builtin_amdgcn_mfma_f32_16x16x32_bf16(qf1, b1, sa[s], 0, 0, 0);
    }
    // scores
    #pragma unroll
    for (int i = 0; i < 16; ++i) {
      float x = sa[i >> 2][i & 3] * 0.125f + bv[i] * bscale;
      bv[i] = ((mb >> i) & 1u) ? -1e30f : x;
    }
    // online softmax (rows live across the 16 lanes of my g-group)
    float mnew[4], scl[4];
    #pragma unroll
    for (int r = 0; r < 4; ++r) {
      float mx = fmaxf(fmaxf(bv[r], bv[4 + r]), fmaxf(bv[8 + r], bv[12 + r]));
      #pragma unroll
      for (int off = 1; off < 16; off <<= 1) mx = fmaxf(mx, __shfl_xor(mx, off));
      float mn = fmaxf(m_r[r], mx);
      mnew[r] = mn;
      scl[r] = __expf(m_r[r] - mn);
    }
    #pragma unroll
    for (int i = 0; i < 16; ++i) {
      float pv = ((mb >> i) & 1u) ? 0.f : __expf(bv[i] - mnew[i & 3]);
      bv[i] = pv;
    }
    #pragma unroll
    for (int r = 0; r < 4; ++r) {
      float sum = bv[r] + bv[4 + r] + bv[8 + r] + bv[12 + r];
      #pragma unroll
      for (int off = 1; off < 16; off <<= 1) sum += __shfl_xor(sum, off);
      l_r[r] = l_r[r] * scl[r] + sum;
      m_r[r] = mnew[r];
    }
    #pragma unroll
    for (int i = 0; i < 16; ++i)
      p_s[wq][4 * g + (i & 3)][16 * (i >> 2) + c] = f2b(bv[i]);
    #pragma unroll
    for (int s2 = 0; s2 < 4; ++s2) {
      #pragma unroll
      for (int r = 0; r < 4; ++r) o[s2][r] *= scl[r];
    }
    __syncthreads();

    // ---- PV: O[q][dv=16s2+c] += P[q][key] * V[key][dv]
    bf16x8 pa0 = ld8(&p_s[wq][c][8 * g]);
    bf16x8 pa1 = ld8(&p_s[wq][c][32 + 8 * g]);
    #pragma unroll
    for (int s2 = 0; s2 < 4; ++s2) {
      const unsigned short* vrow = &v_t[16 * s2 + c][0];
      bf16x8 v0 = ld8(vrow + 8 * g);
      bf16x8 v1 = ld8(vrow + 32 + 8 * g);
      o[s2] = __builtin_amdgcn_mfma_f32_16x16x32_bf16(pa0, v0, o[s2], 0, 0, 0);
      o[s2] = __builtin_amdgcn_mfma_f32_16x16x32_bf16(pa1, v1, o[s2], 0, 0, 0);
    }
  }
  // epilogue: raw partial (unnormalized O, running m, l)
  const size_t gr0 = (size_t)b * SS + qw;
  #pragma unroll
  for (int s2 = 0; s2 < 4; ++s2) {
    #pragma unroll
    for (int r = 0; r < 4; ++r)
      part_o[((size_t)ks * NR + gr0 + 4 * g + r) * DD + 16 * s2 + c] = o[s2][r];
  }
  if (c < 4) {
    float mm = (c == 0) ? m_r[0] : (c == 1) ? m_r[1] : (c == 2) ? m_r[2] : m_r[3];
    float ll = (c == 0) ? l_r[0] : (c == 1) ? l_r[1] : (c == 2) ? l_r[2] : l_r[3];
    size_t row = (size_t)ks * NR + gr0 + 4 * g + c;
    part_ml[row * 2] = mm;
    part_ml[row * 2 + 1] = ll;
  }
}

// ---------------- combine partials + output projection (fp32) ----------------
__global__ __launch_bounds__(256, 4) void fc_combine(
    const float* __restrict__ part_o, const float* __restrict__ part_ml,
    const float* __restrict__ Wfc, const float* __restrict__ bfc,
    float* __restrict__ out, int nks) {
  const int row0 = blockIdx.x * 16;
  const int tid = threadIdx.x;
  __shared__ float a_s[16][68];
  {
    int rr = tid >> 4, q4 = (tid & 15) * 4;
    size_t grow = (size_t)row0 + rr;
    float M = -1e30f;
    for (int i = 0; i < nks; ++i) M = fmaxf(M, part_ml[((size_t)i * NR + grow) * 2]);
    float L = 0.f;
    float4 oa = {0.f, 0.f, 0.f, 0.f};
    for (int i = 0; i < nks; ++i) {
      float mi = part_ml[((size_t)i * NR + grow) * 2];
      float li = part_ml[((size_t)i * NR + grow) * 2 + 1];
      float w = __expf(mi - M);
      L += li * w;
      float4 ov = *(const float4*)&part_o[((size_t)i * NR + grow) * DD + q4];
      oa.x += w * ov.x; oa.y += w * ov.y; oa.z += w * ov.z; oa.w += w * ov.w;
    }
    float inv = (L > 0.f) ? 1.0f / L : 0.f;
    a_s[rr][q4] = oa.x * inv; a_s[rr][q4 + 1] = oa.y * inv;
    a_s[rr][q4 + 2] = oa.z * inv; a_s[rr][q4 + 3] = oa.w * inv;
  }
  __syncthreads();
  const int r0 = (tid >> 7) * 8;
  const int c0 = (tid & 127) * 4;
  float4 acc[8];
  float4 bb = *(const float4*)(bfc + c0);
  #pragma unroll
  for (int i = 0; i < 8; ++i) acc[i] = bb;
  #pragma unroll 4
  for (int kk = 0; kk < DD; ++kk) {
    float4 w = *(const float4*)(Wfc + (size_t)kk * DM + c0);
    #pragma unroll
    for (int i = 0; i < 8; ++i) {
      float a = a_s[r0 + i][kk];
      acc[i].x += a * w.x; acc[i].y += a * w.y;
      acc[i].z += a * w.z; acc[i].w += a * w.w;
    }
  }
  #pragma unroll
  for (int i = 0; i < 8; ++i)
    *(float4*)(out + (size_t)(row0 + r0 + i) * DM + c0) = acc[i];
}

extern "C" void kernel_launch(void* const* d_in, const int* in_sizes, int n_in,
                              void* d_out, int out_size, void* d_ws, size_t ws_size,
                              hipStream_t stream) {
  const float* q    = (const float*)d_in[0];
  const float* k    = (const float*)d_in[1];
  const float* v    = (const float*)d_in[2];
  const float* gb   = (const float*)d_in[3];
  const void*  mask = d_in[4];
  const float* Wq   = (const float*)d_in[5];
  const float* bq   = (const float*)d_in[6];
  const float* Wk   = (const float*)d_in[7];
  const float* bk   = (const float*)d_in[8];
  const float* Wv   = (const float*)d_in[9];
  const float* bv   = (const float*)d_in[10];
  const float* Wfc  = (const float*)d_in[11];
  const float* bfc  = (const float*)d_in[12];
  const float* tau  = (const float*)d_in[13];
  float* out = (float*)d_out;

  char* ws = (char*)d_ws;
  int* viol = (int*)ws;
  unsigned short* Wt = (unsigned short*)(ws + 1024);          // 3*64*512*2 = 196608
  unsigned short* qp = (unsigned short*)(ws + 197632);
  unsigned short* kp = qp + (size_t)NR * DD;
  unsigned short* vp = kp + (size_t)NR * DD;
  char* pbase = (char*)(vp + (size_t)NR * DD);
  size_t used = (size_t)(pbase - ws);
  size_t per = (size_t)NR * DD * 4 + (size_t)NR * 2 * 4;      // part_o + part_ml per split
  int nks = 1;
  if (ws_size >= used + 8 * per) nks = 8;
  else if (ws_size >= used + 4 * per) nks = 4;
  else if (ws_size >= used + 2 * per) nks = 2;
  float* part_o = (float*)pbase;
  float* part_ml = part_o + (size_t)nks * NR * DD;

  init_flags<<<1, 64, 0, stream>>>(viol);
  detect_mask<<<1024, 256, 0, stream>>>((const unsigned*)mask, in_sizes[4] / 4, viol);
  transpose_w<<<dim3(8, 3), 256, 0, stream>>>(Wq, Wk, Wv, Wt);
  proj_mfma<<<dim3(NR / 64, 3), 256, 0, stream>>>(q, k, v, Wt, bq, bk, bv, qp, kp, vp);
  attn_mfma<<<dim3((SS / 64) * nks, NB), 256, 0, stream>>>(
      qp, kp, vp, gb, mask, viol, tau, part_o, part_ml, nks);
  fc_combine<<<NR / 16, 256, 0, stream>>>(part_o, part_ml, Wfc, bfc, out, nks);
}

// Round 4
// 101.610 us; speedup vs baseline: 3.7622x; 1.3004x over previous
//
#include <hip/hip_runtime.h>

#define NB 4
#define SS 2048
#define DM 512
#define DD 64
#define NR (NB*SS)

typedef __attribute__((ext_vector_type(8))) short bf16x8;
typedef __attribute__((ext_vector_type(4))) float f32x4;

static __device__ __forceinline__ unsigned short f2b(float f) {
  union { float f; unsigned u; } x; x.f = f;
  unsigned r = x.u + 0x7FFFu + ((x.u >> 16) & 1u);
  return (unsigned short)(r >> 16);
}
static __device__ __forceinline__ bf16x8 ld8(const unsigned short* p) {
  union { uint4 u; bf16x8 v; } x; x.u = *(const uint4*)p; return x.v;
}

// ---------------- mask dtype detection (per-block flags, no atomic storm) ----------------
__global__ __launch_bounds__(256) void detect_mask(const unsigned* __restrict__ mw,
                                                   int nwords, int* __restrict__ part) {
  int stride = gridDim.x * blockDim.x;
  int vi = 0, vf = 0, vu = 0;
  for (int i = blockIdx.x * blockDim.x + threadIdx.x; i < nwords; i += stride) {
    unsigned w = mw[i];
    vi |= (w > 1u);
    vf |= ((w != 0u) & (w != 0x3F800000u));
    vu |= ((w & 0xFEFEFEFEu) != 0u);
  }
  __shared__ int sh[3];
  if (threadIdx.x < 3) sh[threadIdx.x] = 0;
  __syncthreads();
  int lane = threadIdx.x & 63;
  unsigned long long b;
  b = __ballot(vi); if (lane == 0 && b) sh[0] = 1;   // benign same-value races
  b = __ballot(vf); if (lane == 0 && b) sh[1] = 1;
  b = __ballot(vu); if (lane == 0 && b) sh[2] = 1;
  __syncthreads();
  if (threadIdx.x < 3) part[blockIdx.x * 4 + threadIdx.x] = sh[threadIdx.x];
}

__global__ __launch_bounds__(256) void reduce_flags(const int* __restrict__ part,
                                                    int nblk, int* __restrict__ viol) {
  int j = threadIdx.x;
  int a0 = 0, a1 = 0, a2 = 0;
  for (int i = j; i < nblk; i += 256) {
    a0 |= part[i * 4]; a1 |= part[i * 4 + 1]; a2 |= part[i * 4 + 2];
  }
  __shared__ int sh[3];
  if (j < 3) sh[j] = 0;
  __syncthreads();
  unsigned long long b0 = __ballot(a0), b1 = __ballot(a1), b2 = __ballot(a2);
  if ((j & 63) == 0) {
    if (b0) sh[0] = 1;
    if (b1) sh[1] = 1;
    if (b2) sh[2] = 1;
  }
  __syncthreads();
  if (j < 3) viol[j] = sh[j];
}

// ---------------- W transpose: Wt[p][n=64][k=512] bf16 <- W[k][n] fp32 ----------------
__global__ __launch_bounds__(256) void transpose_w(
    const float* __restrict__ Wq, const float* __restrict__ Wk, const float* __restrict__ Wv,
    unsigned short* __restrict__ Wt) {
  const int p = blockIdx.y;
  const float* W = (p == 0) ? Wq : ((p == 1) ? Wk : Wv);
  const int k0 = blockIdx.x * 64;
  const int t = threadIdx.x;
  const int n0 = (t & 15) * 4;
  #pragma unroll
  for (int p2 = 0; p2 < 4; ++p2) {
    int k = k0 + (t >> 4) + 16 * p2;
    float4 w = *(const float4*)(W + (size_t)k * DD + n0);
    Wt[(size_t)(p * DD + n0 + 0) * DM + k] = f2b(w.x);
    Wt[(size_t)(p * DD + n0 + 1) * DM + k] = f2b(w.y);
    Wt[(size_t)(p * DD + n0 + 2) * DM + k] = f2b(w.z);
    Wt[(size_t)(p * DD + n0 + 3) * DM + k] = f2b(w.w);
  }
}

// ---------------- projections via MFMA: [8192,512]@[512,64] -> bf16 ----------------
__global__ __launch_bounds__(256, 4) void proj_mfma(
    const float* __restrict__ q, const float* __restrict__ k, const float* __restrict__ v,
    const unsigned short* __restrict__ Wt,
    const float* __restrict__ bq, const float* __restrict__ bk, const float* __restrict__ bv,
    unsigned short* __restrict__ qp, unsigned short* __restrict__ kp,
    unsigned short* __restrict__ vp) {
  const int p = blockIdx.y;
  const float* X = (p == 0) ? q : ((p == 1) ? k : v);
  const float* bias = (p == 0) ? bq : ((p == 1) ? bk : bv);
  unsigned short* out = (p == 0) ? qp : ((p == 1) ? kp : vp);
  const int row0 = blockIdx.x * 64;
  const int tid = threadIdx.x;
  const int wq = tid >> 6, lane = tid & 63, g = lane >> 4, c = lane & 15;
  __shared__ unsigned short x_s[64][72];
  f32x4 acc[4];
  #pragma unroll
  for (int s = 0; s < 4; ++s) acc[s] = (f32x4){0.f, 0.f, 0.f, 0.f};
  const unsigned short* wbase = Wt + (size_t)p * DD * DM;

  for (int k0 = 0; k0 < DM; k0 += 64) {
    __syncthreads();
    #pragma unroll
    for (int pp = 0; pp < 4; ++pp) {
      int f = tid + 256 * pp;
      int r = f >> 4, c4 = (f & 15) * 4;
      float4 xv = *(const float4*)(X + (size_t)(row0 + r) * DM + k0 + c4);
      uint2 u;
      u.x = (unsigned)f2b(xv.x) | ((unsigned)f2b(xv.y) << 16);
      u.y = (unsigned)f2b(xv.z) | ((unsigned)f2b(xv.w) << 16);
      *(uint2*)&x_s[r][c4] = u;
    }
    __syncthreads();
    const unsigned short* xrow = &x_s[wq * 16 + c][0];
    bf16x8 a0 = ld8(xrow + 8 * g);
    bf16x8 a1 = ld8(xrow + 32 + 8 * g);
    #pragma unroll
    for (int s = 0; s < 4; ++s) {
      const unsigned short* wrow = wbase + (size_t)(16 * s + c) * DM + k0;
      bf16x8 b0 = ld8(wrow + 8 * g);
      bf16x8 b1 = ld8(wrow + 32 + 8 * g);
      acc[s] = __builtin_amdgcn_mfma_f32_16x16x32_bf16(a0, b0, acc[s], 0, 0, 0);
      acc[s] = __builtin_amdgcn_mfma_f32_16x16x32_bf16(a1, b1, acc[s], 0, 0, 0);
    }
  }
  #pragma unroll
  for (int s = 0; s < 4; ++s) {
    float bs = bias[16 * s + c];
    #pragma unroll
    for (int r = 0; r < 4; ++r) {
      int row = row0 + wq * 16 + 4 * g + r;
      out[(size_t)row * DD + 16 * s + c] = f2b(acc[s][r] + bs);
    }
  }
}

// bias + mask tile loader (16 logits per thread); word mode covers int32 AND fp32
static __device__ __forceinline__ void load_bm(
    bool bytemode, const float* __restrict__ g_bias, const void* __restrict__ mask,
    const size_t* rb, int c, int k0, float* bv, unsigned& mb) {
  mb = 0;
  if (!bytemode) {
    const unsigned* mp = (const unsigned*)mask;
    #pragma unroll
    for (int i = 0; i < 16; ++i) {
      size_t idx = rb[i & 3] + k0 + 16 * (i >> 2) + c;
      bv[i] = g_bias[idx];
      mb |= (mp[idx] != 0u) ? (1u << i) : 0u;
    }
  } else {
    const unsigned char* mp = (const unsigned char*)mask;
    #pragma unroll
    for (int i = 0; i < 16; ++i) {
      size_t idx = rb[i & 3] + k0 + 16 * (i >> 2) + c;
      bv[i] = g_bias[idx];
      mb |= (mp[idx] != 0) ? (1u << i) : 0u;
    }
  }
}

// ---------------- flash attention via MFMA, k-split partials, pipelined ----------------
__global__ __launch_bounds__(256, 4) void attn_mfma(
    const unsigned short* __restrict__ qp, const unsigned short* __restrict__ kp,
    const unsigned short* __restrict__ vp, const float* __restrict__ g_bias,
    const void* __restrict__ mask, const int* __restrict__ viol,
    const float* __restrict__ tau, float* __restrict__ part_o,
    float* __restrict__ part_ml, int nks) {
  const int b = blockIdx.y;
  const int qb = blockIdx.x / nks;
  const int ks = blockIdx.x - qb * nks;
  const int tid = threadIdx.x;
  const int wq = tid >> 6, lane = tid & 63, g = lane >> 4, c = lane & 15;
  const int qw = qb * 64 + wq * 16;
  const int klen = SS / nks, kbeg = ks * klen;
  const bool bytemode = (viol[0] != 0) && (viol[1] != 0);
  const float tv = tau[0];
  const float bscale = 1.0f / (2.0f * tv * tv);

  __shared__ unsigned short k_s[64][72];
  __shared__ unsigned short v_t[64][72];
  __shared__ unsigned short p_s[4][16][72];

  const unsigned short* qrow = qp + (size_t)(b * SS + qw + c) * DD;
  bf16x8 qf0 = ld8(qrow + 8 * g);
  bf16x8 qf1 = ld8(qrow + 32 + 8 * g);

  size_t rb[4];
  #pragma unroll
  for (int r = 0; r < 4; ++r) rb[r] = (size_t)(b * SS + qw + 4 * g + r) * SS;

  // staging thread mapping
  const int krow = tid >> 2, kch = (tid & 3) * 8;          // K: row, col8
  const int vkk = (tid & 31) * 2, vdv = (tid >> 5) * 8;    // V: key pair, dv8
  const unsigned short* kbase = kp + (size_t)b * SS * DD;
  const unsigned short* vbase = vp + (size_t)b * SS * DD;

  float m_r[4] = {-1e30f, -1e30f, -1e30f, -1e30f};
  float l_r[4] = {0.f, 0.f, 0.f, 0.f};
  f32x4 o[4];
  #pragma unroll
  for (int s = 0; s < 4; ++s) o[s] = (f32x4){0.f, 0.f, 0.f, 0.f};

  // ---- prologue: issue tile-0 K/V + bias/mask loads
  uint4 kA = *(const uint4*)(kbase + (size_t)(kbeg + krow) * DD + kch);
  uint4 kB = *(const uint4*)(kbase + (size_t)(kbeg + krow) * DD + 32 + kch);
  uint4 vA = *(const uint4*)(vbase + (size_t)(kbeg + vkk) * DD + vdv);
  uint4 vB = *(const uint4*)(vbase + (size_t)(kbeg + vkk + 1) * DD + vdv);
  float bvc[16];
  unsigned mbc;
  load_bm(bytemode, g_bias, mask, rb, c, kbeg, bvc, mbc);

  for (int kt = 0; kt < klen; kt += 64) {
    const int k0 = kbeg + kt;
    const bool more = (kt + 64) < klen;
    __syncthreads();                           // prev tile's LDS reads done
    {  // write staged regs to LDS (vmcnt waits on loads issued a full tile ago)
      *(uint4*)&k_s[krow][kch] = kA;
      *(uint4*)&k_s[krow][32 + kch] = kB;
      unsigned au[4] = {vA.x, vA.y, vA.z, vA.w};
      unsigned bu[4] = {vB.x, vB.y, vB.z, vB.w};
      #pragma unroll
      for (int i = 0; i < 4; ++i) {
        *(unsigned*)&v_t[vdv + 2 * i][vkk] = (au[i] & 0xFFFFu) | (bu[i] << 16);
        *(unsigned*)&v_t[vdv + 2 * i + 1][vkk] = (au[i] >> 16) | (bu[i] & 0xFFFF0000u);
      }
    }
    if (more) {  // issue next tile's K/V loads now; consumed next iteration
      kA = *(const uint4*)(kbase + (size_t)(k0 + 64 + krow) * DD + kch);
      kB = *(const uint4*)(kbase + (size_t)(k0 + 64 + krow) * DD + 32 + kch);
      vA = *(const uint4*)(vbase + (size_t)(k0 + 64 + vkk) * DD + vdv);
      vB = *(const uint4*)(vbase + (size_t)(k0 + 64 + vkk + 1) * DD + vdv);
    }
    __syncthreads();                           // LDS tiles ready

    // ---- QK^T: S[q=4g+r][key=16s+c]
    f32x4 sa[4];
    #pragma unroll
    for (int s = 0; s < 4; ++s) sa[s] = (f32x4){0.f, 0.f, 0.f, 0.f};
    #pragma unroll
    for (int s = 0; s < 4; ++s) {
      const unsigned short* krw = &k_s[16 * s + c][0];
      bf16x8 b0 = ld8(krw + 8 * g);
      bf16x8 b1 = ld8(krw + 32 + 8 * g);
      sa[s] = __builtin_amdgcn_mfma_f32_16x16x32_bf16(qf0, b0, sa[s], 0, 0, 0);
      sa[s] = __builtin_amdgcn_mfma_f32_16x16x32_bf16(qf1, b1, sa[s], 0, 0, 0);
    }
    // scores (consume current bias/mask)
    float sc[16];
    #pragma unroll
    for (int i = 0; i < 16; ++i) {
      float x = sa[i >> 2][i & 3] * 0.125f + bvc[i] * bscale;
      sc[i] = ((mbc >> i) & 1u) ? -1e30f : x;
    }
    // online softmax (rows live across the 16 lanes of my g-group)
    float mnew[4], scl[4];
    #pragma unroll
    for (int r = 0; r < 4; ++r) {
      float mx = fmaxf(fmaxf(sc[r], sc[4 + r]), fmaxf(sc[8 + r], sc[12 + r]));
      #pragma unroll
      for (int off = 1; off < 16; off <<= 1) mx = fmaxf(mx, __shfl_xor(mx, off));
      float mn = fmaxf(m_r[r], mx);
      mnew[r] = mn;
      scl[r] = __expf(m_r[r] - mn);
    }
    #pragma unroll
    for (int i = 0; i < 16; ++i)
      sc[i] = ((mbc >> i) & 1u) ? 0.f : __expf(sc[i] - mnew[i & 3]);
    #pragma unroll
    for (int r = 0; r < 4; ++r) {
      float sum = sc[r] + sc[4 + r] + sc[8 + r] + sc[12 + r];
      #pragma unroll
      for (int off = 1; off < 16; off <<= 1) sum += __shfl_xor(sum, off);
      l_r[r] = l_r[r] * scl[r] + sum;
      m_r[r] = mnew[r];
    }
    #pragma unroll
    for (int i = 0; i < 16; ++i)
      p_s[wq][4 * g + (i & 3)][16 * (i >> 2) + c] = f2b(sc[i]);
    // issue next tile's bias/mask loads — overlap PV + next staging + next QK
    if (more) load_bm(bytemode, g_bias, mask, rb, c, k0 + 64, bvc, mbc);
    #pragma unroll
    for (int s2 = 0; s2 < 4; ++s2) {
      #pragma unroll
      for (int r = 0; r < 4; ++r) o[s2][r] *= scl[r];
    }
    __syncthreads();                           // p_s visible

    // ---- PV: O[q][dv=16s2+c] += P[q][key] * V[key][dv]
    bf16x8 pa0 = ld8(&p_s[wq][c][8 * g]);
    bf16x8 pa1 = ld8(&p_s[wq][c][32 + 8 * g]);
    #pragma unroll
    for (int s2 = 0; s2 < 4; ++s2) {
      const unsigned short* vrow = &v_t[16 * s2 + c][0];
      bf16x8 v0 = ld8(vrow + 8 * g);
      bf16x8 v1 = ld8(vrow + 32 + 8 * g);
      o[s2] = __builtin_amdgcn_mfma_f32_16x16x32_bf16(pa0, v0, o[s2], 0, 0, 0);
      o[s2] = __builtin_amdgcn_mfma_f32_16x16x32_bf16(pa1, v1, o[s2], 0, 0, 0);
    }
  }
  // epilogue: raw partial (unnormalized O, running m, l)
  const size_t gr0 = (size_t)b * SS + qw;
  #pragma unroll
  for (int s2 = 0; s2 < 4; ++s2) {
    #pragma unroll
    for (int r = 0; r < 4; ++r)
      part_o[((size_t)ks * NR + gr0 + 4 * g + r) * DD + 16 * s2 + c] = o[s2][r];
  }
  if (c < 4) {
    float mm = (c == 0) ? m_r[0] : (c == 1) ? m_r[1] : (c == 2) ? m_r[2] : m_r[3];
    float ll = (c == 0) ? l_r[0] : (c == 1) ? l_r[1] : (c == 2) ? l_r[2] : l_r[3];
    size_t row = (size_t)ks * NR + gr0 + 4 * g + c;
    part_ml[row * 2] = mm;
    part_ml[row * 2 + 1] = ll;
  }
}

// ---------------- combine partials + output projection (fp32) ----------------
__global__ __launch_bounds__(256, 4) void fc_combine(
    const float* __restrict__ part_o, const float* __restrict__ part_ml,
    const float* __restrict__ Wfc, const float* __restrict__ bfc,
    float* __restrict__ out, int nks) {
  const int row0 = blockIdx.x * 16;
  const int tid = threadIdx.x;
  __shared__ float a_s[16][68];
  {
    int rr = tid >> 4, q4 = (tid & 15) * 4;
    size_t grow = (size_t)row0 + rr;
    float M = -1e30f;
    for (int i = 0; i < nks; ++i) M = fmaxf(M, part_ml[((size_t)i * NR + grow) * 2]);
    float L = 0.f;
    float4 oa = {0.f, 0.f, 0.f, 0.f};
    for (int i = 0; i < nks; ++i) {
      float mi = part_ml[((size_t)i * NR + grow) * 2];
      float li = part_ml[((size_t)i * NR + grow) * 2 + 1];
      float w = __expf(mi - M);
      L += li * w;
      float4 ov = *(const float4*)&part_o[((size_t)i * NR + grow) * DD + q4];
      oa.x += w * ov.x; oa.y += w * ov.y; oa.z += w * ov.z; oa.w += w * ov.w;
    }
    float inv = (L > 0.f) ? 1.0f / L : 0.f;
    a_s[rr][q4] = oa.x * inv; a_s[rr][q4 + 1] = oa.y * inv;
    a_s[rr][q4 + 2] = oa.z * inv; a_s[rr][q4 + 3] = oa.w * inv;
  }
  __syncthreads();
  const int r0 = (tid >> 7) * 8;
  const int c0 = (tid & 127) * 4;
  float4 acc[8];
  float4 bb = *(const float4*)(bfc + c0);
  #pragma unroll
  for (int i = 0; i < 8; ++i) acc[i] = bb;
  #pragma unroll 4
  for (int kk = 0; kk < DD; ++kk) {
    float4 w = *(const float4*)(Wfc + (size_t)kk * DM + c0);
    #pragma unroll
    for (int i = 0; i < 8; ++i) {
      float a = a_s[r0 + i][kk];
      acc[i].x += a * w.x; acc[i].y += a * w.y;
      acc[i].z += a * w.z; acc[i].w += a * w.w;
    }
  }
  #pragma unroll
  for (int i = 0; i < 8; ++i)
    *(float4*)(out + (size_t)(row0 + r0 + i) * DM + c0) = acc[i];
}

extern "C" void kernel_launch(void* const* d_in, const int* in_sizes, int n_in,
                              void* d_out, int out_size, void* d_ws, size_t ws_size,
                              hipStream_t stream) {
  const float* q    = (const float*)d_in[0];
  const float* k    = (const float*)d_in[1];
  const float* v    = (const float*)d_in[2];
  const float* gb   = (const float*)d_in[3];
  const void*  mask = d_in[4];
  const float* Wq   = (const float*)d_in[5];
  const float* bq   = (const float*)d_in[6];
  const float* Wk   = (const float*)d_in[7];
  const float* bk   = (const float*)d_in[8];
  const float* Wv   = (const float*)d_in[9];
  const float* bv   = (const float*)d_in[10];
  const float* Wfc  = (const float*)d_in[11];
  const float* bfc  = (const float*)d_in[12];
  const float* tau  = (const float*)d_in[13];
  float* out = (float*)d_out;

  char* ws = (char*)d_ws;
  int* viol = (int*)ws;                                       // 3 ints
  int* part = (int*)(ws + 256);                               // 256 blocks * 4 ints
  unsigned short* Wt = (unsigned short*)(ws + 8192);          // 3*64*512*2 = 196608
  unsigned short* qp = (unsigned short*)(ws + 8192 + 196608);
  unsigned short* kp = qp + (size_t)NR * DD;
  unsigned short* vp = kp + (size_t)NR * DD;
  char* pbase = (char*)(vp + (size_t)NR * DD);
  size_t used = (size_t)(pbase - ws);
  size_t per = (size_t)NR * DD * 4 + (size_t)NR * 2 * 4;      // part_o + part_ml per split
  int nks = 1;
  if (ws_size >= used + 8 * per) nks = 8;
  else if (ws_size >= used + 4 * per) nks = 4;
  else if (ws_size >= used + 2 * per) nks = 2;
  float* part_o = (float*)pbase;
  float* part_ml = part_o + (size_t)nks * NR * DD;

  detect_mask<<<256, 256, 0, stream>>>((const unsigned*)mask, in_sizes[4] / 4, part);
  reduce_flags<<<1, 256, 0, stream>>>(part, 256, viol);
  transpose_w<<<dim3(8, 3), 256, 0, stream>>>(Wq, Wk, Wv, Wt);
  proj_mfma<<<dim3(NR / 64, 3), 256, 0, stream>>>(q, k, v, Wt, bq, bk, bv, qp, kp, vp);
  attn_mfma<<<dim3((SS / 64) * nks, NB), 256, 0, stream>>>(
      qp, kp, vp, gb, mask, viol, tau, part_o, part_ml, nks);
  fc_combine<<<NR / 16, 256, 0, stream>>>(part_o, part_ml, Wfc, bfc, out, nks);
}

// Round 5
// 85.227 us; speedup vs baseline: 4.4854x; 1.1922x over previous
//
#include <hip/hip_runtime.h>

#define NB 4
#define SS 2048
#define DM 512
#define DD 64
#define NR (NB*SS)

typedef __attribute__((ext_vector_type(8))) short bf16x8;
typedef __attribute__((ext_vector_type(4))) float f32x4;

static __device__ __forceinline__ unsigned short f2b(float f) {
  union { float f; unsigned u; } x; x.f = f;
  unsigned r = x.u + 0x7FFFu + ((x.u >> 16) & 1u);
  return (unsigned short)(r >> 16);
}
static __device__ __forceinline__ bf16x8 ld8(const unsigned short* p) {
  union { uint4 u; bf16x8 v; } x; x.u = *(const uint4*)p; return x.v;
}

// ------- mask dtype detection: stride-64 sampled scan (262K samples) -------
__global__ __launch_bounds__(256) void detect_mask(const unsigned* __restrict__ mw,
                                                   int nwords, int* __restrict__ part) {
  const int gid = blockIdx.x * 256 + threadIdx.x;
  const int nthr = gridDim.x * 256;
  int vi = 0, vf = 0, vu = 0;
  for (long i = (long)gid * 64; i < nwords; i += (long)nthr * 64) {
    unsigned w = mw[i];
    vi |= (w > 1u);
    vf |= ((w != 0u) & (w != 0x3F800000u));
    vu |= ((w & 0xFEFEFEFEu) != 0u);
  }
  __shared__ int sh[3];
  if (threadIdx.x < 3) sh[threadIdx.x] = 0;
  __syncthreads();
  int lane = threadIdx.x & 63;
  unsigned long long b;
  b = __ballot(vi); if (lane == 0 && b) sh[0] = 1;   // benign same-value races
  b = __ballot(vf); if (lane == 0 && b) sh[1] = 1;
  b = __ballot(vu); if (lane == 0 && b) sh[2] = 1;
  __syncthreads();
  if (threadIdx.x < 3) part[blockIdx.x * 4 + threadIdx.x] = sh[threadIdx.x];
}

__global__ __launch_bounds__(256) void reduce_flags(const int* __restrict__ part,
                                                    int nblk, int* __restrict__ viol) {
  int j = threadIdx.x;
  int a0 = 0, a1 = 0, a2 = 0;
  for (int i = j; i < nblk; i += 256) {
    a0 |= part[i * 4]; a1 |= part[i * 4 + 1]; a2 |= part[i * 4 + 2];
  }
  __shared__ int sh[3];
  if (j < 3) sh[j] = 0;
  __syncthreads();
  unsigned long long b0 = __ballot(a0), b1 = __ballot(a1), b2 = __ballot(a2);
  if ((j & 63) == 0) {
    if (b0) sh[0] = 1;
    if (b1) sh[1] = 1;
    if (b2) sh[2] = 1;
  }
  __syncthreads();
  if (j < 3) viol[j] = sh[j];
}

// ------- Wq/Wk/Wv transpose: Wt[p][n=64][k=512] bf16 <- W[k][n] fp32 -------
__global__ __launch_bounds__(256) void transpose_w(
    const float* __restrict__ Wq, const float* __restrict__ Wk, const float* __restrict__ Wv,
    unsigned short* __restrict__ Wt) {
  const int p = blockIdx.y;
  const float* W = (p == 0) ? Wq : ((p == 1) ? Wk : Wv);
  const int k0 = blockIdx.x * 64;
  const int t = threadIdx.x;
  const int n0 = (t & 15) * 4;
  #pragma unroll
  for (int p2 = 0; p2 < 4; ++p2) {
    int k = k0 + (t >> 4) + 16 * p2;
    float4 w = *(const float4*)(W + (size_t)k * DD + n0);
    Wt[(size_t)(p * DD + n0 + 0) * DM + k] = f2b(w.x);
    Wt[(size_t)(p * DD + n0 + 1) * DM + k] = f2b(w.y);
    Wt[(size_t)(p * DD + n0 + 2) * DM + k] = f2b(w.z);
    Wt[(size_t)(p * DD + n0 + 3) * DM + k] = f2b(w.w);
  }
}

// ------- Wfc transpose: WfcT[n=512][k=64] bf16 <- Wfc[64][512] fp32 -------
__global__ __launch_bounds__(256) void transpose_wfc(
    const float* __restrict__ Wfc, unsigned short* __restrict__ WfcT) {
  const int n0 = blockIdx.x * 64;
  const int t = threadIdx.x;
  __shared__ unsigned short wt[64][68];   // [k][n]
  {
    int k = t >> 2, j = (t & 3) * 16;
    #pragma unroll
    for (int u = 0; u < 4; ++u) {
      float4 w = *(const float4*)(Wfc + (size_t)k * DM + n0 + j + 4 * u);
      wt[k][j + 4 * u + 0] = f2b(w.x);
      wt[k][j + 4 * u + 1] = f2b(w.y);
      wt[k][j + 4 * u + 2] = f2b(w.z);
      wt[k][j + 4 * u + 3] = f2b(w.w);
    }
  }
  __syncthreads();
  {
    int n = t >> 2, kq = (t & 3) * 16;
    unsigned short tmp[16];
    #pragma unroll
    for (int u = 0; u < 16; ++u) tmp[u] = wt[kq + u][n];
    *(uint4*)(WfcT + (size_t)(n0 + n) * DD + kq) = *(uint4*)&tmp[0];
    *(uint4*)(WfcT + (size_t)(n0 + n) * DD + kq + 8) = *(uint4*)&tmp[8];
  }
}

// ------- projections via MFMA: [8192,512]@[512,64] -> bf16 -------
__global__ __launch_bounds__(256, 4) void proj_mfma(
    const float* __restrict__ q, const float* __restrict__ k, const float* __restrict__ v,
    const unsigned short* __restrict__ Wt,
    const float* __restrict__ bq, const float* __restrict__ bk, const float* __restrict__ bv,
    unsigned short* __restrict__ qp, unsigned short* __restrict__ kp,
    unsigned short* __restrict__ vp) {
  const int p = blockIdx.y;
  const float* X = (p == 0) ? q : ((p == 1) ? k : v);
  const float* bias = (p == 0) ? bq : ((p == 1) ? bk : bv);
  unsigned short* out = (p == 0) ? qp : ((p == 1) ? kp : vp);
  const int row0 = blockIdx.x * 64;
  const int tid = threadIdx.x;
  const int wq = tid >> 6, lane = tid & 63, g = lane >> 4, c = lane & 15;
  __shared__ unsigned short x_s[64][72];
  f32x4 acc[4];
  #pragma unroll
  for (int s = 0; s < 4; ++s) acc[s] = (f32x4){0.f, 0.f, 0.f, 0.f};
  const unsigned short* wbase = Wt + (size_t)p * DD * DM;

  for (int k0 = 0; k0 < DM; k0 += 64) {
    __syncthreads();
    #pragma unroll
    for (int pp = 0; pp < 4; ++pp) {
      int f = tid + 256 * pp;
      int r = f >> 4, c4 = (f & 15) << 2;
      float4 xv = *(const float4*)(X + (size_t)(row0 + r) * DM + k0 + c4);
      uint2 u;
      u.x = (unsigned)f2b(xv.x) | ((unsigned)f2b(xv.y) << 16);
      u.y = (unsigned)f2b(xv.z) | ((unsigned)f2b(xv.w) << 16);
      *(uint2*)&x_s[r][c4] = u;
    }
    __syncthreads();
    const unsigned short* xrow = &x_s[wq * 16 + c][0];
    bf16x8 a0 = ld8(xrow + 8 * g);
    bf16x8 a1 = ld8(xrow + 32 + 8 * g);
    #pragma unroll
    for (int s = 0; s < 4; ++s) {
      const unsigned short* wrow = wbase + (size_t)(16 * s + c) * DM + k0;
      bf16x8 b0 = ld8(wrow + 8 * g);
      bf16x8 b1 = ld8(wrow + 32 + 8 * g);
      acc[s] = __builtin_amdgcn_mfma_f32_16x16x32_bf16(a0, b0, acc[s], 0, 0, 0);
      acc[s] = __builtin_amdgcn_mfma_f32_16x16x32_bf16(a1, b1, acc[s], 0, 0, 0);
    }
  }
  #pragma unroll
  for (int s = 0; s < 4; ++s) {
    float bs = bias[16 * s + c];
    #pragma unroll
    for (int r = 0; r < 4; ++r) {
      int row = row0 + wq * 16 + 4 * g + r;
      out[(size_t)row * DD + 16 * s + c] = f2b(acc[s][r] + bs);
    }
  }
}

// bias + mask tile loader (16 logits per thread); word mode covers int32 AND fp32
static __device__ __forceinline__ void load_bm(
    bool bytemode, const float* __restrict__ g_bias, const void* __restrict__ mask,
    const size_t* rb, int c, int k0, float* bv, unsigned& mb) {
  mb = 0;
  if (!bytemode) {
    const unsigned* mp = (const unsigned*)mask;
    #pragma unroll
    for (int i = 0; i < 16; ++i) {
      size_t idx = rb[i & 3] + k0 + 16 * (i >> 2) + c;
      bv[i] = g_bias[idx];
      mb |= (mp[idx] != 0u) ? (1u << i) : 0u;
    }
  } else {
    const unsigned char* mp = (const unsigned char*)mask;
    #pragma unroll
    for (int i = 0; i < 16; ++i) {
      size_t idx = rb[i & 3] + k0 + 16 * (i >> 2) + c;
      bv[i] = g_bias[idx];
      mb |= (mp[idx] != 0) ? (1u << i) : 0u;
    }
  }
}

// ------- flash attention via MFMA, k-split partials (round-3 loop) -------
__global__ __launch_bounds__(256, 4) void attn_mfma(
    const unsigned short* __restrict__ qp, const unsigned short* __restrict__ kp,
    const unsigned short* __restrict__ vp, const float* __restrict__ g_bias,
    const void* __restrict__ mask, const int* __restrict__ viol,
    const float* __restrict__ tau, float* __restrict__ part_o,
    float* __restrict__ part_ml, int nks) {
  const int b = blockIdx.y;
  const int qb = blockIdx.x / nks;
  const int ks = blockIdx.x - qb * nks;
  const int tid = threadIdx.x;
  const int wq = tid >> 6, lane = tid & 63, g = lane >> 4, c = lane & 15;
  const int qw = qb * 64 + wq * 16;
  const int klen = SS / nks, kbeg = ks * klen;
  const bool bytemode = (viol[0] != 0) && (viol[1] != 0) && (viol[2] == 0);
  const float tv = tau[0];
  const float bscale = 1.0f / (2.0f * tv * tv);

  __shared__ unsigned short k_s[64][72];
  __shared__ unsigned short v_t[64][72];
  __shared__ unsigned short p_s[4][16][72];

  const unsigned short* qrow = qp + (size_t)(b * SS + qw + c) * DD;
  bf16x8 qf0 = ld8(qrow + 8 * g);
  bf16x8 qf1 = ld8(qrow + 32 + 8 * g);

  size_t rb[4];
  #pragma unroll
  for (int r = 0; r < 4; ++r) rb[r] = (size_t)(b * SS + qw + 4 * g + r) * SS;

  float m_r[4] = {-1e30f, -1e30f, -1e30f, -1e30f};
  float l_r[4] = {0.f, 0.f, 0.f, 0.f};
  f32x4 o[4];
  #pragma unroll
  for (int s = 0; s < 4; ++s) o[s] = (f32x4){0.f, 0.f, 0.f, 0.f};

  for (int kt = 0; kt < klen; kt += 64) {
    const int k0 = kbeg + kt;
    __syncthreads();
    {  // stage K tile [key][dk] and V tile transposed [dv][key]
      int row = tid >> 2, ch = (tid & 3) * 8;
      const unsigned short* ksrc = kp + (size_t)(b * SS + k0 + row) * DD + ch;
      *(uint4*)&k_s[row][ch] = *(const uint4*)ksrc;
      *(uint4*)&k_s[row][32 + ch] = *(const uint4*)(ksrc + 32);
      int kk = (tid & 31) * 2, dv0 = (tid >> 5) * 8;
      const unsigned short* va = vp + (size_t)(b * SS + k0 + kk) * DD + dv0;
      uint4 aa = *(const uint4*)va;
      uint4 bb = *(const uint4*)(va + DD);
      unsigned au[4] = {aa.x, aa.y, aa.z, aa.w};
      unsigned bu[4] = {bb.x, bb.y, bb.z, bb.w};
      #pragma unroll
      for (int i = 0; i < 4; ++i) {
        *(unsigned*)&v_t[dv0 + 2 * i][kk] = (au[i] & 0xFFFFu) | (bu[i] << 16);
        *(unsigned*)&v_t[dv0 + 2 * i + 1][kk] = (au[i] >> 16) | (bu[i] & 0xFFFF0000u);
      }
    }
    // bias + mask loads (issued in staging window, consumed post-QK)
    float bvc[16];
    unsigned mbc;
    load_bm(bytemode, g_bias, mask, rb, c, k0, bvc, mbc);
    __syncthreads();

    // ---- QK^T: S[q=4g+r][key=16s+c]
    f32x4 sa[4];
    #pragma unroll
    for (int s = 0; s < 4; ++s) sa[s] = (f32x4){0.f, 0.f, 0.f, 0.f};
    #pragma unroll
    for (int s = 0; s < 4; ++s) {
      const unsigned short* krw = &k_s[16 * s + c][0];
      bf16x8 b0 = ld8(krw + 8 * g);
      bf16x8 b1 = ld8(krw + 32 + 8 * g);
      sa[s] = __builtin_amdgcn_mfma_f32_16x16x32_bf16(qf0, b0, sa[s], 0, 0, 0);
      sa[s] = __builtin_amdgcn_mfma_f32_16x16x32_bf16(qf1, b1, sa[s], 0, 0, 0);
    }
    float sc[16];
    #pragma unroll
    for (int i = 0; i < 16; ++i) {
      float x = sa[i >> 2][i & 3] * 0.125f + bvc[i] * bscale;
      sc[i] = ((mbc >> i) & 1u) ? -1e30f : x;
    }
    // online softmax (rows live across the 16 lanes of my g-group)
    float mnew[4], scl[4];
    #pragma unroll
    for (int r = 0; r < 4; ++r) {
      float mx = fmaxf(fmaxf(sc[r], sc[4 + r]), fmaxf(sc[8 + r], sc[12 + r]));
      #pragma unroll
      for (int off = 1; off < 16; off <<= 1) mx = fmaxf(mx, __shfl_xor(mx, off));
      float mn = fmaxf(m_r[r], mx);
      mnew[r] = mn;
      scl[r] = __expf(m_r[r] - mn);
    }
    #pragma unroll
    for (int i = 0; i < 16; ++i)
      sc[i] = ((mbc >> i) & 1u) ? 0.f : __expf(sc[i] - mnew[i & 3]);
    #pragma unroll
    for (int r = 0; r < 4; ++r) {
      float sum = sc[r] + sc[4 + r] + sc[8 + r] + sc[12 + r];
      #pragma unroll
      for (int off = 1; off < 16; off <<= 1) sum += __shfl_xor(sum, off);
      l_r[r] = l_r[r] * scl[r] + sum;
      m_r[r] = mnew[r];
    }
    #pragma unroll
    for (int i = 0; i < 16; ++i)
      p_s[wq][4 * g + (i & 3)][16 * (i >> 2) + c] = f2b(sc[i]);
    #pragma unroll
    for (int s2 = 0; s2 < 4; ++s2) {
      #pragma unroll
      for (int r = 0; r < 4; ++r) o[s2][r] *= scl[r];
    }
    __syncthreads();

    // ---- PV: O[q][dv=16s2+c] += P[q][key] * V[key][dv]
    bf16x8 pa0 = ld8(&p_s[wq][c][8 * g]);
    bf16x8 pa1 = ld8(&p_s[wq][c][32 + 8 * g]);
    #pragma unroll
    for (int s2 = 0; s2 < 4; ++s2) {
      const unsigned short* vrow = &v_t[16 * s2 + c][0];
      bf16x8 v0 = ld8(vrow + 8 * g);
      bf16x8 v1 = ld8(vrow + 32 + 8 * g);
      o[s2] = __builtin_amdgcn_mfma_f32_16x16x32_bf16(pa0, v0, o[s2], 0, 0, 0);
      o[s2] = __builtin_amdgcn_mfma_f32_16x16x32_bf16(pa1, v1, o[s2], 0, 0, 0);
    }
  }
  // epilogue: raw partial (unnormalized O, running m, l)
  const size_t gr0 = (size_t)b * SS + qw;
  #pragma unroll
  for (int s2 = 0; s2 < 4; ++s2) {
    #pragma unroll
    for (int r = 0; r < 4; ++r)
      part_o[((size_t)ks * NR + gr0 + 4 * g + r) * DD + 16 * s2 + c] = o[s2][r];
  }
  if (c < 4) {
    float mm = (c == 0) ? m_r[0] : (c == 1) ? m_r[1] : (c == 2) ? m_r[2] : m_r[3];
    float ll = (c == 0) ? l_r[0] : (c == 1) ? l_r[1] : (c == 2) ? l_r[2] : l_r[3];
    size_t row = (size_t)ks * NR + gr0 + 4 * g + c;
    part_ml[row * 2] = mm;
    part_ml[row * 2 + 1] = ll;
  }
}

// ------- combine partials + output projection via MFMA -------
__global__ __launch_bounds__(256, 4) void fc_mfma(
    const float* __restrict__ part_o, const float* __restrict__ part_ml,
    const unsigned short* __restrict__ WfcT, const float* __restrict__ bfc,
    float* __restrict__ out, int nks) {
  const int row0 = blockIdx.x * 16;
  const int tid = threadIdx.x;
  const int w = tid >> 6, lane = tid & 63, g = lane >> 4, c = lane & 15;
  __shared__ unsigned short a16[16][72];
  {
    int r = tid >> 4, d4 = (tid & 15) * 4;
    size_t grow = (size_t)row0 + r;
    float M = -1e30f;
    for (int i = 0; i < nks; ++i) M = fmaxf(M, part_ml[((size_t)i * NR + grow) * 2]);
    float L = 0.f;
    float4 oa = {0.f, 0.f, 0.f, 0.f};
    for (int i = 0; i < nks; ++i) {
      float mi = part_ml[((size_t)i * NR + grow) * 2];
      float li = part_ml[((size_t)i * NR + grow) * 2 + 1];
      float wgt = __expf(mi - M);
      L += li * wgt;
      float4 ov = *(const float4*)&part_o[((size_t)i * NR + grow) * DD + d4];
      oa.x += wgt * ov.x; oa.y += wgt * ov.y; oa.z += wgt * ov.z; oa.w += wgt * ov.w;
    }
    float inv = (L > 0.f) ? 1.0f / L : 0.f;
    a16[r][d4 + 0] = f2b(oa.x * inv);
    a16[r][d4 + 1] = f2b(oa.y * inv);
    a16[r][d4 + 2] = f2b(oa.z * inv);
    a16[r][d4 + 3] = f2b(oa.w * inv);
  }
  __syncthreads();
  bf16x8 a0 = ld8(&a16[c][8 * g]);
  bf16x8 a1 = ld8(&a16[c][32 + 8 * g]);
  f32x4 acc[8];
  #pragma unroll
  for (int s = 0; s < 8; ++s) acc[s] = (f32x4){0.f, 0.f, 0.f, 0.f};
  #pragma unroll
  for (int s = 0; s < 8; ++s) {
    const unsigned short* bp = WfcT + (size_t)(128 * w + 16 * s + c) * DD;
    bf16x8 b0 = ld8(bp + 8 * g);
    bf16x8 b1 = ld8(bp + 32 + 8 * g);
    acc[s] = __builtin_amdgcn_mfma_f32_16x16x32_bf16(a0, b0, acc[s], 0, 0, 0);
    acc[s] = __builtin_amdgcn_mfma_f32_16x16x32_bf16(a1, b1, acc[s], 0, 0, 0);
  }
  #pragma unroll
  for (int s = 0; s < 8; ++s) {
    int col = 128 * w + 16 * s + c;
    float bb = bfc[col];
    #pragma unroll
    for (int rr = 0; rr < 4; ++rr)
      out[(size_t)(row0 + 4 * g + rr) * DM + col] = acc[s][rr] + bb;
  }
}

extern "C" void kernel_launch(void* const* d_in, const int* in_sizes, int n_in,
                              void* d_out, int out_size, void* d_ws, size_t ws_size,
                              hipStream_t stream) {
  const float* q    = (const float*)d_in[0];
  const float* k    = (const float*)d_in[1];
  const float* v    = (const float*)d_in[2];
  const float* gb   = (const float*)d_in[3];
  const void*  mask = d_in[4];
  const float* Wq   = (const float*)d_in[5];
  const float* bq   = (const float*)d_in[6];
  const float* Wk   = (const float*)d_in[7];
  const float* bk   = (const float*)d_in[8];
  const float* Wv   = (const float*)d_in[9];
  const float* bv   = (const float*)d_in[10];
  const float* Wfc  = (const float*)d_in[11];
  const float* bfc  = (const float*)d_in[12];
  const float* tau  = (const float*)d_in[13];
  float* out = (float*)d_out;

  char* ws = (char*)d_ws;
  int* viol = (int*)ws;                                       // 3 ints
  int* part = (int*)(ws + 256);                               // 64 blocks * 4 ints
  unsigned short* Wt   = (unsigned short*)(ws + 8192);        // 196608 B
  unsigned short* WfcT = (unsigned short*)(ws + 8192 + 196608);  // 65536 B
  unsigned short* qp = (unsigned short*)(ws + 8192 + 196608 + 65536);
  unsigned short* kp = qp + (size_t)NR * DD;
  unsigned short* vp = kp + (size_t)NR * DD;
  char* pbase = (char*)(vp + (size_t)NR * DD);
  size_t used = (size_t)(pbase - ws);
  size_t per = (size_t)NR * DD * 4 + (size_t)NR * 2 * 4;      // part_o + part_ml per split
  int nks = 1;
  if (ws_size >= used + 16 * per) nks = 16;
  else if (ws_size >= used + 8 * per) nks = 8;
  else if (ws_size >= used + 4 * per) nks = 4;
  else if (ws_size >= used + 2 * per) nks = 2;
  float* part_o = (float*)pbase;
  float* part_ml = part_o + (size_t)nks * NR * DD;

  detect_mask<<<64, 256, 0, stream>>>((const unsigned*)mask, in_sizes[4] / 4, part);
  reduce_flags<<<1, 256, 0, stream>>>(part, 64, viol);
  transpose_w<<<dim3(8, 3), 256, 0, stream>>>(Wq, Wk, Wv, Wt);
  transpose_wfc<<<8, 256, 0, stream>>>(Wfc, WfcT);
  proj_mfma<<<dim3(NR / 64, 3), 256, 0, stream>>>(q, k, v, Wt, bq, bk, bv, qp, kp, vp);
  attn_mfma<<<dim3((SS / 64) * nks, NB), 256, 0, stream>>>(
      qp, kp, vp, gb, mask, viol, tau, part_o, part_ml, nks);
  fc_mfma<<<NR / 16, 256, 0, stream>>>(part_o, part_ml, WfcT, bfc, out, nks);
}

// Round 6
// 83.181 us; speedup vs baseline: 4.5957x; 1.0246x over previous
//
#include <hip/hip_runtime.h>

#define NB 4
#define SS 2048
#define DM 512
#define DD 64
#define NR (NB*SS)

typedef __attribute__((ext_vector_type(8))) short bf16x8;
typedef __attribute__((ext_vector_type(4))) float f32x4;

static __device__ __forceinline__ unsigned short f2b(float f) {
  union { float f; unsigned u; } x; x.f = f;
  unsigned r = x.u + 0x7FFFu + ((x.u >> 16) & 1u);
  return (unsigned short)(r >> 16);
}
static __device__ __forceinline__ bf16x8 ld8(const unsigned short* p) {
  union { uint4 u; bf16x8 v; } x; x.u = *(const uint4*)p; return x.v;
}

// ------- mask dtype detection: stride-64 sampled scan -------
__global__ __launch_bounds__(256) void detect_mask(const unsigned* __restrict__ mw,
                                                   int nwords, int* __restrict__ part) {
  const int gid = blockIdx.x * 256 + threadIdx.x;
  const int nthr = gridDim.x * 256;
  int vi = 0, vf = 0, vu = 0;
  for (long i = (long)gid * 64; i < nwords; i += (long)nthr * 64) {
    unsigned w = mw[i];
    vi |= (w > 1u);
    vf |= ((w != 0u) & (w != 0x3F800000u));
    vu |= ((w & 0xFEFEFEFEu) != 0u);
  }
  __shared__ int sh[3];
  if (threadIdx.x < 3) sh[threadIdx.x] = 0;
  __syncthreads();
  int lane = threadIdx.x & 63;
  unsigned long long b;
  b = __ballot(vi); if (lane == 0 && b) sh[0] = 1;   // benign same-value races
  b = __ballot(vf); if (lane == 0 && b) sh[1] = 1;
  b = __ballot(vu); if (lane == 0 && b) sh[2] = 1;
  __syncthreads();
  if (threadIdx.x < 3) part[blockIdx.x * 4 + threadIdx.x] = sh[threadIdx.x];
}

__global__ __launch_bounds__(256) void reduce_flags(const int* __restrict__ part,
                                                    int nblk, int* __restrict__ viol) {
  int j = threadIdx.x;
  int a0 = 0, a1 = 0, a2 = 0;
  for (int i = j; i < nblk; i += 256) {
    a0 |= part[i * 4]; a1 |= part[i * 4 + 1]; a2 |= part[i * 4 + 2];
  }
  __shared__ int sh[3];
  if (j < 3) sh[j] = 0;
  __syncthreads();
  unsigned long long b0 = __ballot(a0), b1 = __ballot(a1), b2 = __ballot(a2);
  if ((j & 63) == 0) {
    if (b0) sh[0] = 1;
    if (b1) sh[1] = 1;
    if (b2) sh[2] = 1;
  }
  __syncthreads();
  if (j < 3) viol[j] = sh[j];
}

// ------- Wq/Wk/Wv transpose: Wt[p][n=64][k=512] bf16 <- W[k][n] fp32 -------
__global__ __launch_bounds__(256) void transpose_w(
    const float* __restrict__ Wq, const float* __restrict__ Wk, const float* __restrict__ Wv,
    unsigned short* __restrict__ Wt) {
  const int p = blockIdx.y;
  const float* W = (p == 0) ? Wq : ((p == 1) ? Wk : Wv);
  const int k0 = blockIdx.x * 64;
  const int t = threadIdx.x;
  const int n0 = (t & 15) * 4;
  #pragma unroll
  for (int p2 = 0; p2 < 4; ++p2) {
    int k = k0 + (t >> 4) + 16 * p2;
    float4 w = *(const float4*)(W + (size_t)k * DD + n0);
    Wt[(size_t)(p * DD + n0 + 0) * DM + k] = f2b(w.x);
    Wt[(size_t)(p * DD + n0 + 1) * DM + k] = f2b(w.y);
    Wt[(size_t)(p * DD + n0 + 2) * DM + k] = f2b(w.z);
    Wt[(size_t)(p * DD + n0 + 3) * DM + k] = f2b(w.w);
  }
}

// ------- Wfc transpose: WfcT[n=512][k=64] bf16 <- Wfc[64][512] fp32 -------
__global__ __launch_bounds__(256) void transpose_wfc(
    const float* __restrict__ Wfc, unsigned short* __restrict__ WfcT) {
  const int n0 = blockIdx.x * 64;
  const int t = threadIdx.x;
  __shared__ unsigned short wt[64][68];   // [k][n]
  {
    int k = t >> 2, j = (t & 3) * 16;
    #pragma unroll
    for (int u = 0; u < 4; ++u) {
      float4 w = *(const float4*)(Wfc + (size_t)k * DM + n0 + j + 4 * u);
      wt[k][j + 4 * u + 0] = f2b(w.x);
      wt[k][j + 4 * u + 1] = f2b(w.y);
      wt[k][j + 4 * u + 2] = f2b(w.z);
      wt[k][j + 4 * u + 3] = f2b(w.w);
    }
  }
  __syncthreads();
  {
    int n = t >> 2, kq = (t & 3) * 16;
    unsigned short tmp[16];
    #pragma unroll
    for (int u = 0; u < 16; ++u) tmp[u] = wt[kq + u][n];
    *(uint4*)(WfcT + (size_t)(n0 + n) * DD + kq) = *(uint4*)&tmp[0];
    *(uint4*)(WfcT + (size_t)(n0 + n) * DD + kq + 8) = *(uint4*)&tmp[8];
  }
}

// ------- projections via MFMA: [8192,512]@[512,64] -> bf16 -------
__global__ __launch_bounds__(256, 4) void proj_mfma(
    const float* __restrict__ q, const float* __restrict__ k, const float* __restrict__ v,
    const unsigned short* __restrict__ Wt,
    const float* __restrict__ bq, const float* __restrict__ bk, const float* __restrict__ bv,
    unsigned short* __restrict__ qp, unsigned short* __restrict__ kp,
    unsigned short* __restrict__ vp) {
  const int p = blockIdx.y;
  const float* X = (p == 0) ? q : ((p == 1) ? k : v);
  const float* bias = (p == 0) ? bq : ((p == 1) ? bk : bv);
  unsigned short* out = (p == 0) ? qp : ((p == 1) ? kp : vp);
  const int row0 = blockIdx.x * 64;
  const int tid = threadIdx.x;
  const int wq = tid >> 6, lane = tid & 63, g = lane >> 4, c = lane & 15;
  __shared__ unsigned short x_s[64][72];
  f32x4 acc[4];
  #pragma unroll
  for (int s = 0; s < 4; ++s) acc[s] = (f32x4){0.f, 0.f, 0.f, 0.f};
  const unsigned short* wbase = Wt + (size_t)p * DD * DM;

  for (int k0 = 0; k0 < DM; k0 += 64) {
    __syncthreads();
    #pragma unroll
    for (int pp = 0; pp < 4; ++pp) {
      int f = tid + 256 * pp;
      int r = f >> 4, c4 = (f & 15) << 2;
      float4 xv = *(const float4*)(X + (size_t)(row0 + r) * DM + k0 + c4);
      uint2 u;
      u.x = (unsigned)f2b(xv.x) | ((unsigned)f2b(xv.y) << 16);
      u.y = (unsigned)f2b(xv.z) | ((unsigned)f2b(xv.w) << 16);
      *(uint2*)&x_s[r][c4] = u;
    }
    __syncthreads();
    const unsigned short* xrow = &x_s[wq * 16 + c][0];
    bf16x8 a0 = ld8(xrow + 8 * g);
    bf16x8 a1 = ld8(xrow + 32 + 8 * g);
    #pragma unroll
    for (int s = 0; s < 4; ++s) {
      const unsigned short* wrow = wbase + (size_t)(16 * s + c) * DM + k0;
      bf16x8 b0 = ld8(wrow + 8 * g);
      bf16x8 b1 = ld8(wrow + 32 + 8 * g);
      acc[s] = __builtin_amdgcn_mfma_f32_16x16x32_bf16(a0, b0, acc[s], 0, 0, 0);
      acc[s] = __builtin_amdgcn_mfma_f32_16x16x32_bf16(a1, b1, acc[s], 0, 0, 0);
    }
  }
  #pragma unroll
  for (int s = 0; s < 4; ++s) {
    float bs = bias[16 * s + c];
    #pragma unroll
    for (int r = 0; r < 4; ++r) {
      int row = row0 + wq * 16 + 4 * g + r;
      out[(size_t)row * DD + 16 * s + c] = f2b(acc[s][r] + bs);
    }
  }
}

// ------- flash attention, SWAPPED QK^T: lane owns one q-row, 4-consecutive keys -------
__global__ __launch_bounds__(256, 4) void attn_mfma(
    const unsigned short* __restrict__ qp, const unsigned short* __restrict__ kp,
    const unsigned short* __restrict__ vp, const float* __restrict__ g_bias,
    const void* __restrict__ mask, const int* __restrict__ viol,
    const float* __restrict__ tau, float* __restrict__ part_o,
    float* __restrict__ part_ml, int nks) {
  const int b = blockIdx.y;
  const int qb = blockIdx.x / nks;
  const int ks = blockIdx.x - qb * nks;
  const int tid = threadIdx.x;
  const int wq = tid >> 6, lane = tid & 63, g = lane >> 4, c = lane & 15;
  const int qw = qb * 64 + wq * 16;
  const int klen = SS / nks, kbeg = ks * klen;
  const bool bytemode = (viol[0] != 0) && (viol[1] != 0) && (viol[2] == 0);
  const float tv = tau[0];
  const float bscale = 1.0f / (2.0f * tv * tv);

  __shared__ unsigned short k_s[64][72];
  __shared__ unsigned short v_t[64][72];
  __shared__ unsigned short p_s[4][16][72];

  // Q fragment (B-operand of swapped QK^T): Q[qw+c][k]
  const unsigned short* qrow = qp + (size_t)(b * SS + qw + c) * DD;
  bf16x8 qf0 = ld8(qrow + 8 * g);
  bf16x8 qf1 = ld8(qrow + 32 + 8 * g);

  // my q-row for bias/mask (one row per lane)
  const size_t rq = (size_t)(b * SS + qw + c) * SS;

  float m_r = -1e30f, l_r = 0.f;
  f32x4 o[4];
  #pragma unroll
  for (int s = 0; s < 4; ++s) o[s] = (f32x4){0.f, 0.f, 0.f, 0.f};

  for (int kt = 0; kt < klen; kt += 64) {
    const int k0 = kbeg + kt;
    __syncthreads();
    {  // stage K tile [key][dk] and V tile transposed [dv][key]
      int row = tid >> 2, ch = (tid & 3) * 8;
      const unsigned short* ksrc = kp + (size_t)(b * SS + k0 + row) * DD + ch;
      *(uint4*)&k_s[row][ch] = *(const uint4*)ksrc;
      *(uint4*)&k_s[row][32 + ch] = *(const uint4*)(ksrc + 32);
      int kk = (tid & 31) * 2, dv0 = (tid >> 5) * 8;
      const unsigned short* va = vp + (size_t)(b * SS + k0 + kk) * DD + dv0;
      uint4 aa = *(const uint4*)va;
      uint4 bb = *(const uint4*)(va + DD);
      unsigned au[4] = {aa.x, aa.y, aa.z, aa.w};
      unsigned bu[4] = {bb.x, bb.y, bb.z, bb.w};
      #pragma unroll
      for (int i = 0; i < 4; ++i) {
        *(unsigned*)&v_t[dv0 + 2 * i][kk] = (au[i] & 0xFFFFu) | (bu[i] << 16);
        *(unsigned*)&v_t[dv0 + 2 * i + 1][kk] = (au[i] >> 16) | (bu[i] & 0xFFFF0000u);
      }
    }
    // bias + mask: VECTOR loads, 4 consecutive keys per s (key base k0+16s+4g)
    f32x4 bv4[4];
    unsigned mb = 0;
    #pragma unroll
    for (int s = 0; s < 4; ++s) {
      const size_t kb = rq + k0 + 16 * s + 4 * g;
      bv4[s] = *(const f32x4*)(g_bias + kb);
      if (!bytemode) {
        uint4 m4 = *(const uint4*)((const unsigned*)mask + kb);
        mb |= ((m4.x != 0u) ? 1u : 0u) << (4 * s);
        mb |= ((m4.y != 0u) ? 1u : 0u) << (4 * s + 1);
        mb |= ((m4.z != 0u) ? 1u : 0u) << (4 * s + 2);
        mb |= ((m4.w != 0u) ? 1u : 0u) << (4 * s + 3);
      } else {
        unsigned mu = *(const unsigned*)((const unsigned char*)mask + kb);
        mb |= ((mu & 0x000000FFu) ? 1u : 0u) << (4 * s);
        mb |= ((mu & 0x0000FF00u) ? 1u : 0u) << (4 * s + 1);
        mb |= ((mu & 0x00FF0000u) ? 1u : 0u) << (4 * s + 2);
        mb |= ((mu & 0xFF000000u) ? 1u : 0u) << (4 * s + 3);
      }
    }
    __syncthreads();

    // ---- swapped QK^T: sa[s][r] = S[q=qw+c][key = k0+16s+4g+r]
    f32x4 sa[4];
    #pragma unroll
    for (int s = 0; s < 4; ++s) sa[s] = (f32x4){0.f, 0.f, 0.f, 0.f};
    #pragma unroll
    for (int s = 0; s < 4; ++s) {
      const unsigned short* krw = &k_s[16 * s + c][0];
      bf16x8 a0 = ld8(krw + 8 * g);
      bf16x8 a1 = ld8(krw + 32 + 8 * g);
      sa[s] = __builtin_amdgcn_mfma_f32_16x16x32_bf16(a0, qf0, sa[s], 0, 0, 0);
      sa[s] = __builtin_amdgcn_mfma_f32_16x16x32_bf16(a1, qf1, sa[s], 0, 0, 0);
    }
    // scores
    float sc[16];
    #pragma unroll
    for (int s = 0; s < 4; ++s) {
      #pragma unroll
      for (int r = 0; r < 4; ++r) {
        float x = sa[s][r] * 0.125f + bv4[s][r] * bscale;
        sc[4 * s + r] = ((mb >> (4 * s + r)) & 1u) ? -1e30f : x;
      }
    }
    // online softmax: row q=c lives across the 4 g-lanes -> 2-step shfl reduce
    float mx = sc[0];
    #pragma unroll
    for (int i = 1; i < 16; ++i) mx = fmaxf(mx, sc[i]);
    mx = fmaxf(mx, __shfl_xor(mx, 16));
    mx = fmaxf(mx, __shfl_xor(mx, 32));
    float mn = fmaxf(m_r, mx);
    float scl = __expf(m_r - mn);
    float sum = 0.f;
    #pragma unroll
    for (int i = 0; i < 16; ++i) {
      sc[i] = __expf(sc[i] - mn);     // masked: exp(-1e30-mn) underflows to 0
      sum += sc[i];
    }
    sum += __shfl_xor(sum, 16);
    sum += __shfl_xor(sum, 32);
    l_r = l_r * scl + sum;
    m_r = mn;
    // P^T -> p_s[wq][q=c][key]: 4 consecutive keys pack into one 8B write
    #pragma unroll
    for (int s = 0; s < 4; ++s) {
      uint2 u;
      u.x = (unsigned)f2b(sc[4 * s]) | ((unsigned)f2b(sc[4 * s + 1]) << 16);
      u.y = (unsigned)f2b(sc[4 * s + 2]) | ((unsigned)f2b(sc[4 * s + 3]) << 16);
      *(uint2*)&p_s[wq][c][16 * s + 4 * g] = u;
    }
    // O rows are q=4g+r -> broadcast scl from lane (c'=4g+r, g'=0)
    float scl4[4];
    #pragma unroll
    for (int r = 0; r < 4; ++r) scl4[r] = __shfl(scl, 4 * g + r);
    #pragma unroll
    for (int s2 = 0; s2 < 4; ++s2) {
      #pragma unroll
      for (int r = 0; r < 4; ++r) o[s2][r] *= scl4[r];
    }
    __syncthreads();

    // ---- PV: O[q=4g+r][dv=16s2+c] += P[q][key] * V[key][dv]
    bf16x8 pa0 = ld8(&p_s[wq][c][8 * g]);
    bf16x8 pa1 = ld8(&p_s[wq][c][32 + 8 * g]);
    #pragma unroll
    for (int s2 = 0; s2 < 4; ++s2) {
      const unsigned short* vrow = &v_t[16 * s2 + c][0];
      bf16x8 v0 = ld8(vrow + 8 * g);
      bf16x8 v1 = ld8(vrow + 32 + 8 * g);
      o[s2] = __builtin_amdgcn_mfma_f32_16x16x32_bf16(pa0, v0, o[s2], 0, 0, 0);
      o[s2] = __builtin_amdgcn_mfma_f32_16x16x32_bf16(pa1, v1, o[s2], 0, 0, 0);
    }
  }
  // epilogue: raw partial (unnormalized O, running m, l)
  const size_t gr0 = (size_t)b * SS + qw;
  #pragma unroll
  for (int s2 = 0; s2 < 4; ++s2) {
    #pragma unroll
    for (int r = 0; r < 4; ++r)
      part_o[((size_t)ks * NR + gr0 + 4 * g + r) * DD + 16 * s2 + c] = o[s2][r];
  }
  if (g == 0) {
    size_t row = (size_t)ks * NR + gr0 + c;
    part_ml[row * 2] = m_r;
    part_ml[row * 2 + 1] = l_r;
  }
}

// ------- combine partials + output projection via MFMA -------
__global__ __launch_bounds__(256, 4) void fc_mfma(
    const float* __restrict__ part_o, const float* __restrict__ part_ml,
    const unsigned short* __restrict__ WfcT, const float* __restrict__ bfc,
    float* __restrict__ out, int nks) {
  const int row0 = blockIdx.x * 16;
  const int tid = threadIdx.x;
  const int w = tid >> 6, lane = tid & 63, g = lane >> 4, c = lane & 15;
  __shared__ unsigned short a16[16][72];
  {
    int r = tid >> 4, d4 = (tid & 15) * 4;
    size_t grow = (size_t)row0 + r;
    float M = -1e30f;
    for (int i = 0; i < nks; ++i) M = fmaxf(M, part_ml[((size_t)i * NR + grow) * 2]);
    float L = 0.f;
    float4 oa = {0.f, 0.f, 0.f, 0.f};
    for (int i = 0; i < nks; ++i) {
      float mi = part_ml[((size_t)i * NR + grow) * 2];
      float li = part_ml[((size_t)i * NR + grow) * 2 + 1];
      float wgt = __expf(mi - M);
      L += li * wgt;
      float4 ov = *(const float4*)&part_o[((size_t)i * NR + grow) * DD + d4];
      oa.x += wgt * ov.x; oa.y += wgt * ov.y; oa.z += wgt * ov.z; oa.w += wgt * ov.w;
    }
    float inv = (L > 0.f) ? 1.0f / L : 0.f;
    a16[r][d4 + 0] = f2b(oa.x * inv);
    a16[r][d4 + 1] = f2b(oa.y * inv);
    a16[r][d4 + 2] = f2b(oa.z * inv);
    a16[r][d4 + 3] = f2b(oa.w * inv);
  }
  __syncthreads();
  bf16x8 a0 = ld8(&a16[c][8 * g]);
  bf16x8 a1 = ld8(&a16[c][32 + 8 * g]);
  f32x4 acc[8];
  #pragma unroll
  for (int s = 0; s < 8; ++s) acc[s] = (f32x4){0.f, 0.f, 0.f, 0.f};
  #pragma unroll
  for (int s = 0; s < 8; ++s) {
    const unsigned short* bp = WfcT + (size_t)(128 * w + 16 * s + c) * DD;
    bf16x8 b0 = ld8(bp + 8 * g);
    bf16x8 b1 = ld8(bp + 32 + 8 * g);
    acc[s] = __builtin_amdgcn_mfma_f32_16x16x32_bf16(a0, b0, acc[s], 0, 0, 0);
    acc[s] = __builtin_amdgcn_mfma_f32_16x16x32_bf16(a1, b1, acc[s], 0, 0, 0);
  }
  #pragma unroll
  for (int s = 0; s < 8; ++s) {
    int col = 128 * w + 16 * s + c;
    float bb = bfc[col];
    #pragma unroll
    for (int rr = 0; rr < 4; ++rr)
      out[(size_t)(row0 + 4 * g + rr) * DM + col] = acc[s][rr] + bb;
  }
}

extern "C" void kernel_launch(void* const* d_in, const int* in_sizes, int n_in,
                              void* d_out, int out_size, void* d_ws, size_t ws_size,
                              hipStream_t stream) {
  const float* q    = (const float*)d_in[0];
  const float* k    = (const float*)d_in[1];
  const float* v    = (const float*)d_in[2];
  const float* gb   = (const float*)d_in[3];
  const void*  mask = d_in[4];
  const float* Wq   = (const float*)d_in[5];
  const float* bq   = (const float*)d_in[6];
  const float* Wk   = (const float*)d_in[7];
  const float* bk   = (const float*)d_in[8];
  const float* Wv   = (const float*)d_in[9];
  const float* bv   = (const float*)d_in[10];
  const float* Wfc  = (const float*)d_in[11];
  const float* bfc  = (const float*)d_in[12];
  const float* tau  = (const float*)d_in[13];
  float* out = (float*)d_out;

  char* ws = (char*)d_ws;
  int* viol = (int*)ws;                                       // 3 ints
  int* part = (int*)(ws + 256);                               // 64 blocks * 4 ints
  unsigned short* Wt   = (unsigned short*)(ws + 8192);        // 196608 B
  unsigned short* WfcT = (unsigned short*)(ws + 8192 + 196608);  // 65536 B
  unsigned short* qp = (unsigned short*)(ws + 8192 + 196608 + 65536);
  unsigned short* kp = qp + (size_t)NR * DD;
  unsigned short* vp = kp + (size_t)NR * DD;
  char* pbase = (char*)(vp + (size_t)NR * DD);
  size_t used = (size_t)(pbase - ws);
  size_t per = (size_t)NR * DD * 4 + (size_t)NR * 2 * 4;      // part_o + part_ml per split
  int nks = 1;
  if (ws_size >= used + 8 * per) nks = 8;
  else if (ws_size >= used + 4 * per) nks = 4;
  else if (ws_size >= used + 2 * per) nks = 2;
  float* part_o = (float*)pbase;
  float* part_ml = part_o + (size_t)nks * NR * DD;

  detect_mask<<<64, 256, 0, stream>>>((const unsigned*)mask, in_sizes[4] / 4, part);
  reduce_flags<<<1, 256, 0, stream>>>(part, 64, viol);
  transpose_w<<<dim3(8, 3), 256, 0, stream>>>(Wq, Wk, Wv, Wt);
  transpose_wfc<<<8, 256, 0, stream>>>(Wfc, WfcT);
  proj_mfma<<<dim3(NR / 64, 3), 256, 0, stream>>>(q, k, v, Wt, bq, bk, bv, qp, kp, vp);
  attn_mfma<<<dim3((SS / 64) * nks, NB), 256, 0, stream>>>(
      qp, kp, vp, gb, mask, viol, tau, part_o, part_ml, nks);
  fc_mfma<<<NR / 16, 256, 0, stream>>>(part_o, part_ml, WfcT, bfc, out, nks);
}